// Round 1
// baseline (2265.507 us; speedup 1.0000x reference)
//
#include <hip/hip_runtime.h>
#include <math.h>

// GeoAB: conv3x3(192->384) -> [window attn | shifted window attn | axial attn] -> conv3x3(192->192)
// B=2, H=W=160, WS=5, NH=8, CPH=8. All fp32.

constexpr int Hc = 160, Wc = 160;
constexpr int Bc = 2;

// ---------------- conv 3x3 SAME, NCHW, fp32, direct ----------------
// grid: (H*W/256, Cout/COPT, B). Weights are wave-uniform (cout group from blockIdx.y) -> s_loads.
template<int CIN, int COPT>
__global__ __launch_bounds__(256)
void conv3x3_kernel(const float* __restrict__ x, const float* __restrict__ w,
                    const float* __restrict__ bias, float* __restrict__ out) {
  const int hw   = blockIdx.x * 256 + threadIdx.x;   // 0..25599
  const int wpos = hw % Wc;
  const int h    = hw / Wc;
  const int cg   = blockIdx.y;
  const int b    = blockIdx.z;
  const int co0  = cg * COPT;
  const int Cout = gridDim.y * COPT;

  float acc[COPT];
#pragma unroll
  for (int j = 0; j < COPT; ++j) acc[j] = bias[co0 + j];

  const float* xb = x + (size_t)b * CIN * Hc * Wc;
  for (int ci = 0; ci < CIN; ++ci) {
    const float* xc = xb + (size_t)ci * Hc * Wc;
    float xv[9];
#pragma unroll
    for (int dy = 0; dy < 3; ++dy) {
      const int hy = h + dy - 1;
      const bool oky = (unsigned)hy < (unsigned)Hc;
#pragma unroll
      for (int dx = 0; dx < 3; ++dx) {
        const int wx = wpos + dx - 1;
        const bool ok = oky && ((unsigned)wx < (unsigned)Wc);
        xv[dy*3+dx] = ok ? xc[hy*Wc + wx] : 0.0f;
      }
    }
    const float* wp = w + ((size_t)co0 * CIN + ci) * 9;
#pragma unroll
    for (int j = 0; j < COPT; ++j) {
#pragma unroll
      for (int k = 0; k < 9; ++k)
        acc[j] = fmaf(xv[k], wp[(size_t)j * CIN * 9 + k], acc[j]);
    }
  }
  float* op = out + (((size_t)b * Cout + co0) * Hc + h) * Wc + wpos;
#pragma unroll
  for (int j = 0; j < COPT; ++j) op[(size_t)j * Hc * Wc] = acc[j];
}

// ---------------- CPB relative-position bias table: 81 entries x 8 heads ----------------
// biasf[entry][head] = 16*sigmoid( relu(t @ W1^T + b1) @ W2^T ), t = signed-log coords
__global__ __launch_bounds__(64)
void cpb_bias_kernel(const float* __restrict__ w1, const float* __restrict__ b1,
                     const float* __restrict__ w2, float* __restrict__ biasf) {
  const int e  = blockIdx.x;        // 0..80
  const int d0 = e / 9, d1 = e % 9;
  const int r0 = d0 - 4, r1 = d1 - 4;
  // t = sign(r)*log2(2|r|+1)/log2(8)
  float t0 = log2f(fabsf((float)r0) * 2.0f + 1.0f) * (1.0f/3.0f); if (r0 < 0) t0 = -t0;
  float t1 = log2f(fabsf((float)r1) * 2.0f + 1.0f) * (1.0f/3.0f); if (r1 < 0) t1 = -t1;

  const int lane = threadIdx.x;
  float acc[8];
#pragma unroll
  for (int n = 0; n < 8; ++n) acc[n] = 0.f;
  for (int k = lane; k < 512; k += 64) {
    float hk = fmaf(t0, w1[k*2+0], fmaf(t1, w1[k*2+1], b1[k]));
    hk = fmaxf(hk, 0.f);
#pragma unroll
    for (int n = 0; n < 8; ++n) acc[n] = fmaf(hk, w2[n*512 + k], acc[n]);
  }
#pragma unroll
  for (int n = 0; n < 8; ++n) {
#pragma unroll
    for (int off = 32; off > 0; off >>= 1) acc[n] += __shfl_xor(acc[n], off, 64);
  }
  if (lane == 0) {
#pragma unroll
    for (int n = 0; n < 8; ++n)
      biasf[e*8 + n] = 16.0f / (1.0f + expf(-acc[n]));
  }
}

// ---------------- 5x5 window cosine attention (optionally shifted) ----------------
// One block per window; tid = head*32 + pos (pos<25 active). q = k = l2norm(k).
__global__ __launch_bounds__(256)
void win_attn_kernel(const float* __restrict__ xp, const float* __restrict__ biasf,
                     const float* __restrict__ logit_scale, float* __restrict__ y,
                     int chan_off, int y_ch_off, int shift_in, int shift_out) {
  __shared__ float kn[8][25][8];
  __shared__ float vv[8][25][8];
  const int head = threadIdx.x >> 5;
  const int i    = threadIdx.x & 31;
  int blk = blockIdx.x;
  const int wb_i = blk % 32; blk /= 32;
  const int hb_i = blk % 32; blk /= 32;
  const int b    = blk;
  const int wi = i / 5, wj = i % 5;
  const int gh = hb_i * 5 + wi, gw = wb_i * 5 + wj;
  const int sh = (gh + shift_in) % Hc, sw = (gw + shift_in) % Wc;
  const size_t bbase = (size_t)b * 384 * Hc * Wc;

  if (i < 25) {
    float k[8]; float nrm = 0.f;
#pragma unroll
    for (int c = 0; c < 8; ++c) {
      k[c] = xp[bbase + (size_t)(chan_off + head*8 + c) * (Hc*Wc) + sh*Wc + sw];
      nrm = fmaf(k[c], k[c], nrm);
    }
    const float inv = 1.0f / fmaxf(sqrtf(nrm), 1e-12f);
#pragma unroll
    for (int c = 0; c < 8; ++c) kn[head][i][c] = k[c] * inv;
#pragma unroll
    for (int c = 0; c < 8; ++c)
      vv[head][i][c] = xp[bbase + (size_t)(chan_off + 64 + head*8 + c) * (Hc*Wc) + sh*Wc + sw];
  }
  __syncthreads();
  if (i >= 25) return;

  const float scale = expf(fminf(logit_scale[head], logf(100.0f)));
  float s[25];
#pragma unroll
  for (int j = 0; j < 25; ++j) {
    float d = 0.f;
#pragma unroll
    for (int c = 0; c < 8; ++c) d = fmaf(kn[head][i][c], kn[head][j][c], d);
    const int d0 = wi - (j/5) + 4, d1 = wj - (j%5) + 4;
    s[j] = d * scale + biasf[(d0*9 + d1)*8 + head];
  }
  float m = -1e30f;
#pragma unroll
  for (int j = 0; j < 25; ++j) m = fmaxf(m, s[j]);
  float den = 0.f, acc[8];
#pragma unroll
  for (int c = 0; c < 8; ++c) acc[c] = 0.f;
#pragma unroll
  for (int j = 0; j < 25; ++j) {
    const float p = expf(s[j] - m);
    den += p;
#pragma unroll
    for (int c = 0; c < 8; ++c) acc[c] = fmaf(p, vv[head][j][c], acc[c]);
  }
  const float rden = 1.0f / den;
  const int oh = (gh + shift_out) % Hc, ow = (gw + shift_out) % Wc;
  float* yp = y + ((size_t)b * 192 + y_ch_off + head*8) * (size_t)(Hc*Wc) + oh*Wc + ow;
#pragma unroll
  for (int c = 0; c < 8; ++c) yp[(size_t)c * Hc * Wc] = acc[c] * rden;
}

// ---------------- axial attention, row pass: per (b,h,head), seq over w ----------------
// vrow layout: [b][head][c][h][w]
__global__ __launch_bounds__(192)
void row_attn_kernel(const float* __restrict__ xp, const float* __restrict__ lrs,
                     float* __restrict__ vrow) {
  __shared__ float kn[160][8];
  __shared__ float vv[160][8];
  int blk = blockIdx.x;
  const int head = blk % 8; blk /= 8;
  const int h    = blk % 160; blk /= 160;
  const int b    = blk;
  const int i = threadIdx.x;   // w position
  const size_t bbase = (size_t)b * 384 * Hc * Wc;

  if (i < 160) {
    float k[8]; float nrm = 0.f;
#pragma unroll
    for (int c = 0; c < 8; ++c) {
      k[c] = xp[bbase + (size_t)(256 + head*8 + c) * (Hc*Wc) + h*Wc + i];
      nrm = fmaf(k[c], k[c], nrm);
    }
    const float inv = 1.0f / fmaxf(sqrtf(nrm), 1e-12f);
#pragma unroll
    for (int c = 0; c < 8; ++c) kn[i][c] = k[c] * inv;
#pragma unroll
    for (int c = 0; c < 8; ++c)
      vv[i][c] = xp[bbase + (size_t)(320 + head*8 + c) * (Hc*Wc) + h*Wc + i];
  }
  __syncthreads();
  if (i >= 160) return;

  const float scale = expf(fminf(lrs[head], logf(100.0f)));
  float q[8];
#pragma unroll
  for (int c = 0; c < 8; ++c) q[c] = kn[i][c];
  float m = -1e30f;
  for (int j = 0; j < 160; ++j) {
    float d = 0.f;
#pragma unroll
    for (int c = 0; c < 8; ++c) d = fmaf(q[c], kn[j][c], d);
    m = fmaxf(m, d * scale);
  }
  float den = 0.f, acc[8];
#pragma unroll
  for (int c = 0; c < 8; ++c) acc[c] = 0.f;
  for (int j = 0; j < 160; ++j) {
    float d = 0.f;
#pragma unroll
    for (int c = 0; c < 8; ++c) d = fmaf(q[c], kn[j][c], d);
    const float p = expf(d * scale - m);
    den += p;
#pragma unroll
    for (int c = 0; c < 8; ++c) acc[c] = fmaf(p, vv[j][c], acc[c]);
  }
  const float rden = 1.0f / den;
  float* vp = vrow + ((((size_t)b*8 + head)*8)*160 + h)*160 + i;
#pragma unroll
  for (int c = 0; c < 8; ++c) vp[(size_t)c*160*160] = acc[c] * rden;
}

// ---------------- axial attention, column pass: per (b,w,head), seq over h ----------------
// k from original x2 channels, v from vrow. Writes y channels 128..191.
__global__ __launch_bounds__(192)
void col_attn_kernel(const float* __restrict__ xp, const float* __restrict__ lrs,
                     const float* __restrict__ vrow, float* __restrict__ y) {
  __shared__ float kn[160][8];
  __shared__ float vv[160][8];
  int blk = blockIdx.x;
  const int head = blk % 8; blk /= 8;
  const int w    = blk % 160; blk /= 160;
  const int b    = blk;
  const int i = threadIdx.x;   // h position
  const size_t bbase = (size_t)b * 384 * Hc * Wc;

  if (i < 160) {
    float k[8]; float nrm = 0.f;
#pragma unroll
    for (int c = 0; c < 8; ++c) {
      k[c] = xp[bbase + (size_t)(256 + head*8 + c) * (Hc*Wc) + (size_t)i*Wc + w];
      nrm = fmaf(k[c], k[c], nrm);
    }
    const float inv = 1.0f / fmaxf(sqrtf(nrm), 1e-12f);
#pragma unroll
    for (int c = 0; c < 8; ++c) kn[i][c] = k[c] * inv;
#pragma unroll
    for (int c = 0; c < 8; ++c)
      vv[i][c] = vrow[((((size_t)b*8 + head)*8 + c)*160 + i)*160 + w];
  }
  __syncthreads();
  if (i >= 160) return;

  const float scale = expf(fminf(lrs[head], logf(100.0f)));
  float q[8];
#pragma unroll
  for (int c = 0; c < 8; ++c) q[c] = kn[i][c];
  float m = -1e30f;
  for (int j = 0; j < 160; ++j) {
    float d = 0.f;
#pragma unroll
    for (int c = 0; c < 8; ++c) d = fmaf(q[c], kn[j][c], d);
    m = fmaxf(m, d * scale);
  }
  float den = 0.f, acc[8];
#pragma unroll
  for (int c = 0; c < 8; ++c) acc[c] = 0.f;
  for (int j = 0; j < 160; ++j) {
    float d = 0.f;
#pragma unroll
    for (int c = 0; c < 8; ++c) d = fmaf(q[c], kn[j][c], d);
    const float p = expf(d * scale - m);
    den += p;
#pragma unroll
    for (int c = 0; c < 8; ++c) acc[c] = fmaf(p, vv[j][c], acc[c]);
  }
  const float rden = 1.0f / den;
  float* yp = y + ((size_t)b * 192 + 128 + head*8) * (size_t)(Hc*Wc) + (size_t)i*Wc + w;
#pragma unroll
  for (int c = 0; c < 8; ++c) yp[(size_t)c * Hc * Wc] = acc[c] * rden;
}

extern "C" void kernel_launch(void* const* d_in, const int* in_sizes, int n_in,
                              void* d_out, int out_size, void* d_ws, size_t ws_size,
                              hipStream_t stream) {
  const float* x     = (const float*)d_in[0];
  const float* w_in  = (const float*)d_in[1];
  const float* b_in  = (const float*)d_in[2];
  const float* w_out = (const float*)d_in[3];
  const float* b_out = (const float*)d_in[4];
  const float* ls    = (const float*)d_in[5];
  const float* lrs   = (const float*)d_in[6];
  const float* cw1   = (const float*)d_in[7];
  const float* cb1   = (const float*)d_in[8];
  const float* cw2   = (const float*)d_in[9];
  float* out = (float*)d_out;

  // workspace layout (floats)
  float* xp    = (float*)d_ws;                        // (2,384,160,160) = 19,660,800
  float* y     = xp   + (size_t)Bc*384*Hc*Wc;         // (2,192,160,160) =  9,830,400
  float* vrow  = y    + (size_t)Bc*192*Hc*Wc;         // (2,8,8,160,160) =  3,276,800
  float* biasf = vrow + (size_t)Bc*8*8*Hc*Wc;         // 81*8 = 648
  // total ~131 MB

  // 1) conv_in 192->384
  conv3x3_kernel<192, 8><<<dim3(Hc*Wc/256, 384/8, Bc), 256, 0, stream>>>(x, w_in, b_in, xp);
  // 2) CPB bias table
  cpb_bias_kernel<<<81, 64, 0, stream>>>(cw1, cb1, cw2, biasf);
  // 3) window attention (branch 0) -> y[:, 0:64]
  win_attn_kernel<<<Bc*32*32, 256, 0, stream>>>(xp, biasf, ls, y, 0, 0, 0, 0);
  // 4) shifted window attention (branch 1): in-shift +3 (roll -3), out-shift +2 (roll +2) -> y[:, 64:128]
  win_attn_kernel<<<Bc*32*32, 256, 0, stream>>>(xp, biasf, ls, y, 128, 64, 3, 2);
  // 5) axial row pass -> vrow
  row_attn_kernel<<<Bc*160*8, 192, 0, stream>>>(xp, lrs, vrow);
  // 6) axial column pass -> y[:, 128:192]
  col_attn_kernel<<<Bc*160*8, 192, 0, stream>>>(xp, lrs, vrow, y);
  // 7) conv_out 192->192
  conv3x3_kernel<192, 8><<<dim3(Hc*Wc/256, 192/8, Bc), 256, 0, stream>>>(y, w_out, b_out, out);
}

// Round 2
// 528.062 us; speedup vs baseline: 4.2902x; 4.2902x over previous
//
#include <hip/hip_runtime.h>
#include <math.h>

// GeoAB: conv3x3(192->384, bf16 MFMA) -> [window attn | shifted window attn | axial attn]
//        -> conv3x3(192->192, bf16 MFMA).  B=2, H=W=160, WS=5, NH=8, CPH=8.

typedef __attribute__((ext_vector_type(8))) short short8;
typedef __attribute__((ext_vector_type(4))) float f32x4;

constexpr int Hc = 160, Wc = 160, Bc = 2;

__device__ inline unsigned short f2bf(float f) {
  union { float f; unsigned u; } v; v.f = f;
  unsigned r = v.u + 0x7FFF + ((v.u >> 16) & 1);
  return (unsigned short)(r >> 16);
}
__device__ inline float bf2f(unsigned short h) {
  union { unsigned u; float f; } v; v.u = ((unsigned)h) << 16;
  return v.f;
}

// ---------------- NCHW fp32 -> NHWC bf16 transpose ----------------
__global__ __launch_bounds__(256)
void nchw2nhwc_bf16(const float* __restrict__ x, unsigned short* __restrict__ xt) {
  __shared__ float tile[192][33];
  int blk = blockIdx.x;
  const int w0 = (blk % 5) * 32; blk /= 5;
  const int h = blk % 160;
  const int b = blk / 160;
  const int t = threadIdx.x;
  for (int i = t; i < 192 * 32; i += 256) {
    int c = i >> 5, w = i & 31;
    tile[c][w] = x[(((size_t)b * 192 + c) * 160 + h) * 160 + w0 + w];
  }
  __syncthreads();
  for (int i = t; i < 32 * 192; i += 256) {
    int w = i / 192, c = i % 192;
    xt[(((size_t)b * 160 + h) * 160 + w0 + w) * 192 + c] = f2bf(tile[c][w]);
  }
}

// ---------------- weights OIHW fp32 -> [tap][co][ci] bf16 ----------------
__global__ __launch_bounds__(256)
void wtransform(const float* __restrict__ w, unsigned short* __restrict__ wtr, int CO, int CI) {
  int id = blockIdx.x * 256 + threadIdx.x;
  if (id >= CO * CI) return;
  const float* wp = w + (size_t)id * 9;
#pragma unroll
  for (int tap = 0; tap < 9; ++tap)
    wtr[(size_t)tap * CO * CI + id] = f2bf(wp[tap]);
}

// ---------------- conv3x3 SAME via implicit GEMM, bf16 MFMA ----------------
// in: xt NHWC bf16 [B][H][W][CIN]; weights wtr [9][COUT][CIN] bf16; out fp32 NCHW.
// grid: (H, COUT/64, B); block 256 = 4 waves (2 w-halves x 2 co-halves).
template<int CIN, int COUT>
__global__ __launch_bounds__(256)
void conv_mfma(const unsigned short* __restrict__ xt, const unsigned short* __restrict__ wtr,
               const float* __restrict__ bias, float* __restrict__ out) {
  __shared__ unsigned short Bl[162][40];      // x slab: row wi -> global w = wi-1; 32 k (+pad)
  __shared__ unsigned short Wl[3][64][40];    // weights: kx, co, 32 ci (+pad)
  const int t = threadIdx.x;
  const int h = blockIdx.x, cog = blockIdx.y, b = blockIdx.z;
  const int lane = t & 63, wid = t >> 6;
  const int wrow = wid >> 1, wcol = wid & 1;
  const int l15 = lane & 15, l4 = lane >> 4;
  const int k0 = l4 * 8;

  const int cobase = cog * 64 + wcol * 32;
  f32x4 binit[2];
#pragma unroll
  for (int ct = 0; ct < 2; ++ct)
#pragma unroll
    for (int r = 0; r < 4; ++r) binit[ct][r] = bias[cobase + ct * 16 + l4 * 4 + r];
  f32x4 acc[5][2];
#pragma unroll
  for (int mt = 0; mt < 5; ++mt) { acc[mt][0] = binit[0]; acc[mt][1] = binit[1]; }

  for (int ky = 0; ky < 3; ++ky) {
    const int hy = h + ky - 1;
    const bool hok = (unsigned)hy < (unsigned)Hc;
    for (int cs = 0; cs < CIN / 32; ++cs) {
      // stage x slab: 162 rows x 32 bf16 (4x16B pieces per row)
      for (int idx = t; idx < 162 * 4; idx += 256) {
        const int row = idx >> 2, part = idx & 3;
        const int g = row - 1;
        short8 v = {};
        if (hok && (unsigned)g < (unsigned)Wc)
          v = *(const short8*)(xt + (((size_t)b * Hc + hy) * Wc + g) * CIN + cs * 32 + part * 8);
        *(short8*)&Bl[row][part * 8] = v;
      }
      // stage weights for 3 kx taps: 3*64 rows x 32 bf16
      for (int idx = t; idx < 768; idx += 256) {
        const int kx = idx >> 8, rem = idx & 255, co = rem >> 2, part = rem & 3;
        short8 v = *(const short8*)(wtr +
            (((size_t)(ky * 3 + kx) * COUT + cog * 64 + co) * CIN + cs * 32 + part * 8));
        *(short8*)&Wl[kx][co][part * 8] = v;
      }
      __syncthreads();
#pragma unroll
      for (int kx = 0; kx < 3; ++kx) {
        short8 a0 = *(const short8*)&Wl[kx][wcol * 32 + l15][k0];
        short8 a1 = *(const short8*)&Wl[kx][wcol * 32 + 16 + l15][k0];
#pragma unroll
        for (int mt = 0; mt < 5; ++mt) {
          short8 bf = *(const short8*)&Bl[wrow * 80 + mt * 16 + l15 + kx][k0];
          acc[mt][0] = __builtin_amdgcn_mfma_f32_16x16x32_bf16(a0, bf, acc[mt][0], 0, 0, 0);
          acc[mt][1] = __builtin_amdgcn_mfma_f32_16x16x32_bf16(a1, bf, acc[mt][1], 0, 0, 0);
        }
      }
      __syncthreads();
    }
  }
  // epilogue: D row = co (within tile: l4*4+r), col = w (l15)
#pragma unroll
  for (int mt = 0; mt < 5; ++mt) {
    const int wv = wrow * 80 + mt * 16 + l15;
#pragma unroll
    for (int ct = 0; ct < 2; ++ct) {
#pragma unroll
      for (int r = 0; r < 4; ++r) {
        const int co = cobase + ct * 16 + l4 * 4 + r;
        out[(((size_t)b * COUT + co) * Hc + h) * Wc + wv] = acc[mt][ct][r];
      }
    }
  }
}

// ---------------- CPB relative-position bias table: 81 entries x 8 heads ----------------
__global__ __launch_bounds__(64)
void cpb_bias_kernel(const float* __restrict__ w1, const float* __restrict__ b1,
                     const float* __restrict__ w2, float* __restrict__ biasf) {
  const int e = blockIdx.x;
  const int d0 = e / 9, d1 = e % 9;
  const int r0 = d0 - 4, r1 = d1 - 4;
  float t0 = log2f(fabsf((float)r0) * 2.0f + 1.0f) * (1.0f / 3.0f); if (r0 < 0) t0 = -t0;
  float t1 = log2f(fabsf((float)r1) * 2.0f + 1.0f) * (1.0f / 3.0f); if (r1 < 0) t1 = -t1;

  const int lane = threadIdx.x;
  float acc[8];
#pragma unroll
  for (int n = 0; n < 8; ++n) acc[n] = 0.f;
  for (int k = lane; k < 512; k += 64) {
    float hk = fmaf(t0, w1[k * 2 + 0], fmaf(t1, w1[k * 2 + 1], b1[k]));
    hk = fmaxf(hk, 0.f);
#pragma unroll
    for (int n = 0; n < 8; ++n) acc[n] = fmaf(hk, w2[n * 512 + k], acc[n]);
  }
#pragma unroll
  for (int n = 0; n < 8; ++n) {
#pragma unroll
    for (int off = 32; off > 0; off >>= 1) acc[n] += __shfl_xor(acc[n], off, 64);
  }
  if (lane == 0) {
#pragma unroll
    for (int n = 0; n < 8; ++n)
      biasf[e * 8 + n] = 16.0f / (1.0f + expf(-acc[n]));
  }
}

// ---------------- 5x5 window cosine attention (optionally shifted) ----------------
// writes yt NHWC bf16 channels [y_ch_off, y_ch_off+64)
__global__ __launch_bounds__(256)
void win_attn_kernel(const float* __restrict__ xp, const float* __restrict__ biasf,
                     const float* __restrict__ logit_scale, unsigned short* __restrict__ yt,
                     int chan_off, int y_ch_off, int shift_in, int shift_out) {
  __shared__ float kn[8][25][8];
  __shared__ float vv[8][25][8];
  const int head = threadIdx.x >> 5;
  const int i = threadIdx.x & 31;
  int blk = blockIdx.x;
  const int wb_i = blk % 32; blk /= 32;
  const int hb_i = blk % 32; blk /= 32;
  const int b = blk;
  const int wi = i / 5, wj = i % 5;
  const int gh = hb_i * 5 + wi, gw = wb_i * 5 + wj;
  const int sh = (gh + shift_in) % Hc, sw = (gw + shift_in) % Wc;
  const size_t bbase = (size_t)b * 384 * Hc * Wc;

  if (i < 25) {
    float k[8]; float nrm = 0.f;
#pragma unroll
    for (int c = 0; c < 8; ++c) {
      k[c] = xp[bbase + (size_t)(chan_off + head * 8 + c) * (Hc * Wc) + sh * Wc + sw];
      nrm = fmaf(k[c], k[c], nrm);
    }
    const float inv = 1.0f / fmaxf(sqrtf(nrm), 1e-12f);
#pragma unroll
    for (int c = 0; c < 8; ++c) kn[head][i][c] = k[c] * inv;
#pragma unroll
    for (int c = 0; c < 8; ++c)
      vv[head][i][c] = xp[bbase + (size_t)(chan_off + 64 + head * 8 + c) * (Hc * Wc) + sh * Wc + sw];
  }
  __syncthreads();
  if (i >= 25) return;

  const float scale = expf(fminf(logit_scale[head], logf(100.0f)));
  float s[25];
#pragma unroll
  for (int j = 0; j < 25; ++j) {
    float d = 0.f;
#pragma unroll
    for (int c = 0; c < 8; ++c) d = fmaf(kn[head][i][c], kn[head][j][c], d);
    const int d0 = wi - (j / 5) + 4, d1 = wj - (j % 5) + 4;
    s[j] = d * scale + biasf[(d0 * 9 + d1) * 8 + head];
  }
  float m = -1e30f;
#pragma unroll
  for (int j = 0; j < 25; ++j) m = fmaxf(m, s[j]);
  float den = 0.f, acc[8];
#pragma unroll
  for (int c = 0; c < 8; ++c) acc[c] = 0.f;
#pragma unroll
  for (int j = 0; j < 25; ++j) {
    const float p = expf(s[j] - m);
    den += p;
#pragma unroll
    for (int c = 0; c < 8; ++c) acc[c] = fmaf(p, vv[head][j][c], acc[c]);
  }
  const float rden = 1.0f / den;
  const int oh = (gh + shift_out) % Hc, ow = (gw + shift_out) % Wc;
  short8 o;
#pragma unroll
  for (int c = 0; c < 8; ++c) o[c] = (short)f2bf(acc[c] * rden);
  *(short8*)(yt + (((size_t)b * Hc + oh) * Wc + ow) * 192 + y_ch_off + head * 8) = o;
}

// ---------------- axial attention, row pass -> vrow bf16 [b][head][c][h][w] ----------------
__global__ __launch_bounds__(192)
void row_attn_kernel(const float* __restrict__ xp, const float* __restrict__ lrs,
                     unsigned short* __restrict__ vrow) {
  __shared__ float kn[160][8];
  __shared__ float vv[160][8];
  int blk = blockIdx.x;
  const int head = blk % 8; blk /= 8;
  const int h = blk % 160; blk /= 160;
  const int b = blk;
  const int i = threadIdx.x;
  const size_t bbase = (size_t)b * 384 * Hc * Wc;

  if (i < 160) {
    float k[8]; float nrm = 0.f;
#pragma unroll
    for (int c = 0; c < 8; ++c) {
      k[c] = xp[bbase + (size_t)(256 + head * 8 + c) * (Hc * Wc) + h * Wc + i];
      nrm = fmaf(k[c], k[c], nrm);
    }
    const float inv = 1.0f / fmaxf(sqrtf(nrm), 1e-12f);
#pragma unroll
    for (int c = 0; c < 8; ++c) kn[i][c] = k[c] * inv;
#pragma unroll
    for (int c = 0; c < 8; ++c)
      vv[i][c] = xp[bbase + (size_t)(320 + head * 8 + c) * (Hc * Wc) + h * Wc + i];
  }
  __syncthreads();
  if (i >= 160) return;

  const float scale = expf(fminf(lrs[head], logf(100.0f)));
  float q[8];
#pragma unroll
  for (int c = 0; c < 8; ++c) q[c] = kn[i][c];
  float m = -1e30f;
  for (int j = 0; j < 160; ++j) {
    float d = 0.f;
#pragma unroll
    for (int c = 0; c < 8; ++c) d = fmaf(q[c], kn[j][c], d);
    m = fmaxf(m, d * scale);
  }
  float den = 0.f, acc[8];
#pragma unroll
  for (int c = 0; c < 8; ++c) acc[c] = 0.f;
  for (int j = 0; j < 160; ++j) {
    float d = 0.f;
#pragma unroll
    for (int c = 0; c < 8; ++c) d = fmaf(q[c], kn[j][c], d);
    const float p = expf(d * scale - m);
    den += p;
#pragma unroll
    for (int c = 0; c < 8; ++c) acc[c] = fmaf(p, vv[j][c], acc[c]);
  }
  const float rden = 1.0f / den;
  unsigned short* vp = vrow + ((((size_t)b * 8 + head) * 8) * 160 + h) * 160 + i;
#pragma unroll
  for (int c = 0; c < 8; ++c) vp[(size_t)c * 160 * 160] = f2bf(acc[c] * rden);
}

// ---------------- axial attention, column pass -> yt channels 128..191 ----------------
__global__ __launch_bounds__(192)
void col_attn_kernel(const float* __restrict__ xp, const float* __restrict__ lrs,
                     const unsigned short* __restrict__ vrow, unsigned short* __restrict__ yt) {
  __shared__ float kn[160][8];
  __shared__ float vv[160][8];
  int blk = blockIdx.x;
  const int head = blk % 8; blk /= 8;
  const int w = blk % 160; blk /= 160;
  const int b = blk;
  const int i = threadIdx.x;
  const size_t bbase = (size_t)b * 384 * Hc * Wc;

  if (i < 160) {
    float k[8]; float nrm = 0.f;
#pragma unroll
    for (int c = 0; c < 8; ++c) {
      k[c] = xp[bbase + (size_t)(256 + head * 8 + c) * (Hc * Wc) + (size_t)i * Wc + w];
      nrm = fmaf(k[c], k[c], nrm);
    }
    const float inv = 1.0f / fmaxf(sqrtf(nrm), 1e-12f);
#pragma unroll
    for (int c = 0; c < 8; ++c) kn[i][c] = k[c] * inv;
#pragma unroll
    for (int c = 0; c < 8; ++c)
      vv[i][c] = bf2f(vrow[((((size_t)b * 8 + head) * 8 + c) * 160 + i) * 160 + w]);
  }
  __syncthreads();
  if (i >= 160) return;

  const float scale = expf(fminf(lrs[head], logf(100.0f)));
  float q[8];
#pragma unroll
  for (int c = 0; c < 8; ++c) q[c] = kn[i][c];
  float m = -1e30f;
  for (int j = 0; j < 160; ++j) {
    float d = 0.f;
#pragma unroll
    for (int c = 0; c < 8; ++c) d = fmaf(q[c], kn[j][c], d);
    m = fmaxf(m, d * scale);
  }
  float den = 0.f, acc[8];
#pragma unroll
  for (int c = 0; c < 8; ++c) acc[c] = 0.f;
  for (int j = 0; j < 160; ++j) {
    float d = 0.f;
#pragma unroll
    for (int c = 0; c < 8; ++c) d = fmaf(q[c], kn[j][c], d);
    const float p = expf(d * scale - m);
    den += p;
#pragma unroll
    for (int c = 0; c < 8; ++c) acc[c] = fmaf(p, vv[j][c], acc[c]);
  }
  const float rden = 1.0f / den;
  short8 o;
#pragma unroll
  for (int c = 0; c < 8; ++c) o[c] = (short)f2bf(acc[c] * rden);
  *(short8*)(yt + (((size_t)b * Hc + i) * Wc + w) * 192 + 128 + head * 8) = o;
}

extern "C" void kernel_launch(void* const* d_in, const int* in_sizes, int n_in,
                              void* d_out, int out_size, void* d_ws, size_t ws_size,
                              hipStream_t stream) {
  const float* x     = (const float*)d_in[0];
  const float* w_in  = (const float*)d_in[1];
  const float* b_in  = (const float*)d_in[2];
  const float* w_out = (const float*)d_in[3];
  const float* b_out = (const float*)d_in[4];
  const float* ls    = (const float*)d_in[5];
  const float* lrs   = (const float*)d_in[6];
  const float* cw1   = (const float*)d_in[7];
  const float* cb1   = (const float*)d_in[8];
  const float* cw2   = (const float*)d_in[9];
  float* out = (float*)d_out;

  // workspace layout (bytes, 16B aligned)
  char* p = (char*)d_ws;
  unsigned short* xt   = (unsigned short*)p;            p += (size_t)Bc * Hc * Wc * 192 * 2;  // 19.66 MB
  float*          xp   = (float*)p;                     p += (size_t)Bc * 384 * Hc * Wc * 4;  // 78.64 MB
  unsigned short* yt   = (unsigned short*)p;            p += (size_t)Bc * Hc * Wc * 192 * 2;  // 19.66 MB
  unsigned short* vrow = (unsigned short*)p;            p += (size_t)Bc * 64 * Hc * Wc * 2;   //  6.55 MB
  unsigned short* wtr1 = (unsigned short*)p;            p += (size_t)9 * 384 * 192 * 2;       //  1.33 MB
  unsigned short* wtr2 = (unsigned short*)p;            p += (size_t)9 * 192 * 192 * 2;       //  0.66 MB
  float*          biasf= (float*)p;

  // prep
  nchw2nhwc_bf16<<<Bc * 160 * 5, 256, 0, stream>>>(x, xt);
  wtransform<<<(384 * 192 + 255) / 256, 256, 0, stream>>>(w_in, wtr1, 384, 192);
  wtransform<<<(192 * 192 + 255) / 256, 256, 0, stream>>>(w_out, wtr2, 192, 192);
  cpb_bias_kernel<<<81, 64, 0, stream>>>(cw1, cb1, cw2, biasf);
  // conv_in 192->384 (MFMA)
  conv_mfma<192, 384><<<dim3(160, 6, Bc), 256, 0, stream>>>(xt, wtr1, b_in, xp);
  // attention branches
  win_attn_kernel<<<Bc * 32 * 32, 256, 0, stream>>>(xp, biasf, ls, yt, 0, 0, 0, 0);
  win_attn_kernel<<<Bc * 32 * 32, 256, 0, stream>>>(xp, biasf, ls, yt, 128, 64, 3, 2);
  row_attn_kernel<<<Bc * 160 * 8, 192, 0, stream>>>(xp, lrs, vrow);
  col_attn_kernel<<<Bc * 160 * 8, 192, 0, stream>>>(xp, lrs, vrow, yt);
  // conv_out 192->192 (MFMA)
  conv_mfma<192, 192><<<dim3(160, 3, Bc), 256, 0, stream>>>(yt, wtr2, b_out, out);
}

// Round 3
// 357.790 us; speedup vs baseline: 6.3320x; 1.4759x over previous
//
#include <hip/hip_runtime.h>
#include <math.h>

// GeoAB: conv3x3(192->384, bf16 MFMA, global_load_lds) -> [win attn | shifted win attn | axial attn]
//        -> conv3x3(192->192, bf16 MFMA).  B=2, H=W=160, WS=5, NH=8, CPH=8.

typedef __attribute__((ext_vector_type(8))) short short8;
typedef __attribute__((ext_vector_type(4))) short short4v;
typedef __attribute__((ext_vector_type(4))) float f32x4;

constexpr int Hc = 160, Wc = 160, Bc = 2;
constexpr int HP = 162;   // padded spatial

__device__ inline unsigned short f2bf(float f) {
  union { float f; unsigned u; } v; v.f = f;
  unsigned r = v.u + 0x7FFF + ((v.u >> 16) & 1);
  return (unsigned short)(r >> 16);
}
__device__ inline float bf2f(unsigned short h) {
  union { unsigned u; float f; } v; v.u = ((unsigned)h) << 16;
  return v.f;
}

__device__ inline void gl16(const void* g, void* l) {
  __builtin_amdgcn_global_load_lds((const __attribute__((address_space(1))) unsigned int*)g,
                                   (__attribute__((address_space(3))) unsigned int*)l, 16, 0, 0);
}

__device__ inline float dot8(f32x4 a0, f32x4 a1, f32x4 b0, f32x4 b1) {
  float d = a0[0] * b0[0];
  d = fmaf(a0[1], b0[1], d); d = fmaf(a0[2], b0[2], d); d = fmaf(a0[3], b0[3], d);
  d = fmaf(a1[0], b1[0], d); d = fmaf(a1[1], b1[1], d);
  d = fmaf(a1[2], b1[2], d); d = fmaf(a1[3], b1[3], d);
  return d;
}

// ---------------- zero padded buffers (16B chunks, grid-stride) ----------------
__global__ __launch_bounds__(256)
void zero16(unsigned short* __restrict__ p, long nchunks) {
  long i = (long)blockIdx.x * 256 + threadIdx.x;
  const long stride = (long)gridDim.x * 256;
  short8 z = {};
  for (; i < nchunks; i += stride) *(short8*)(p + i * 8) = z;
}

// ---------------- NCHW fp32 -> padded NHWC bf16 ----------------
__global__ __launch_bounds__(256)
void nchw2nhwc_pad(const float* __restrict__ x, unsigned short* __restrict__ xpad) {
  __shared__ float tile[192][33];
  int blk = blockIdx.x;
  const int w0 = (blk % 5) * 32; blk /= 5;
  const int h = blk % 160;
  const int b = blk / 160;
  const int t = threadIdx.x;
  for (int i = t; i < 192 * 32; i += 256) {
    int c = i >> 5, w = i & 31;
    tile[c][w] = x[(((size_t)b * 192 + c) * 160 + h) * 160 + w0 + w];
  }
  __syncthreads();
  for (int i = t; i < 32 * 192; i += 256) {
    int w = i / 192, c = i % 192;
    xpad[(((size_t)b * HP + h + 1) * HP + w0 + w + 1) * 192 + c] = f2bf(tile[c][w]);
  }
}

// ---------------- weights OIHW fp32 -> [tap][co][ci] bf16 ----------------
__global__ __launch_bounds__(256)
void wtransform(const float* __restrict__ w, unsigned short* __restrict__ wtr, int CO, int CI) {
  int id = blockIdx.x * 256 + threadIdx.x;
  if (id >= CO * CI) return;
  const float* wp = w + (size_t)id * 9;
#pragma unroll
  for (int tap = 0; tap < 9; ++tap)
    wtr[(size_t)tap * CO * CI + id] = f2bf(wp[tap]);
}

// ---------------- conv3x3 SAME, implicit GEMM, bf16 MFMA ----------------
// xin: padded NHWC bf16 [B][162][162][CIN]; wtr: [9][COUT][CIN] bf16.
// OUTMODE 0: obf NHWC bf16 [B][160][160][384]; OUTMODE 1: of32 NCHW fp32 [B][COUT][160][160].
// Block: WAVES=2*BH waves; wave (hr,wh) -> tile 80w x 64co (acc 5x4).
// LDS slab [BH+2][162][4 chunks x 8 bf16], storage chunk swizzled c^=((w>>1)&3) via source addr.
template<int CIN, int COUT, int BH, int OUTMODE>
__global__ __launch_bounds__(128 * BH)
void conv_mfma(const unsigned short* __restrict__ xin, const unsigned short* __restrict__ wtr,
               const float* __restrict__ bias, unsigned short* __restrict__ obf,
               float* __restrict__ of32) {
  constexpr int WAVES = 2 * BH;
  constexpr int R = BH + 2;
  constexpr int TOTAL = R * 162 * 4;   // 16B chunks per K-step
  __shared__ unsigned short slab[R * 162 * 32];
  const int t = threadIdx.x, lane = t & 63, wid = t >> 6;
  const int h0 = blockIdx.x * BH, cog = blockIdx.y, b = blockIdx.z;
  const int hr = wid >> 1, wh = wid & 1;
  const int l15 = lane & 15, l4 = lane >> 4;
  const int co0 = cog * 64, wbase = wh * 80;

  f32x4 acc[5][4];
#pragma unroll
  for (int ct = 0; ct < 4; ++ct) {
    f32x4 bi;
#pragma unroll
    for (int r = 0; r < 4; ++r) bi[r] = bias[co0 + ct * 16 + l4 * 4 + r];
#pragma unroll
    for (int mt = 0; mt < 5; ++mt) acc[mt][ct] = bi;
  }

  const size_t rowb = (size_t)b * HP + h0;
  for (int cs = 0; cs < CIN / 32; ++cs) {
    // ---- stage x slab: global_load_lds, source pre-swizzled ----
    for (int ib = wid; ib * 64 < TOTAL; ib += WAVES) {
      const int n = ib * 64 + lane;
      if (n < TOTAL) {
        const int c = n & 3, q = n >> 2;
        const int r = q / 162, wv = q - r * 162;
        const int csrc = c ^ ((wv >> 1) & 3);
        const unsigned short* g = xin + ((rowb + r) * HP + wv) * CIN + cs * 32 + csrc * 8;
        gl16(g, &slab[(size_t)ib * 512]);
      }
    }
    __syncthreads();
    for (int ky = 0; ky < 3; ++ky) {
      short8 a[3][4];
#pragma unroll
      for (int kx = 0; kx < 3; ++kx)
#pragma unroll
        for (int ct = 0; ct < 4; ++ct)
          a[kx][ct] = *(const short8*)(wtr +
              ((size_t)(ky * 3 + kx) * COUT + co0 + ct * 16 + l15) * CIN + cs * 32 + l4 * 8);
      const unsigned short* srow = &slab[(hr + ky) * 162 * 32];
#pragma unroll
      for (int kx = 0; kx < 3; ++kx) {
#pragma unroll
        for (int mt = 0; mt < 5; ++mt) {
          const int wv = wbase + mt * 16 + l15 + kx;
          const int cr = l4 ^ ((wv >> 1) & 3);
          short8 bf = *(const short8*)(srow + wv * 32 + cr * 8);
#pragma unroll
          for (int ct = 0; ct < 4; ++ct)
            acc[mt][ct] = __builtin_amdgcn_mfma_f32_16x16x32_bf16(a[kx][ct], bf, acc[mt][ct], 0, 0, 0);
        }
      }
    }
    __syncthreads();
  }
  // ---- epilogue: D row = co (l4*4+r), col = w (l15) ----
  const int h = h0 + hr;
  if (OUTMODE == 0) {
#pragma unroll
    for (int mt = 0; mt < 5; ++mt) {
      const int w = wbase + mt * 16 + l15;
      unsigned short* dst0 = obf + (((size_t)b * Hc + h) * Wc + w) * 384 + co0 + l4 * 4;
#pragma unroll
      for (int ct = 0; ct < 4; ++ct) {
        short4v s;
#pragma unroll
        for (int r = 0; r < 4; ++r) s[r] = (short)f2bf(acc[mt][ct][r]);
        *(short4v*)(dst0 + ct * 16) = s;
      }
    }
  } else {
#pragma unroll
    for (int mt = 0; mt < 5; ++mt) {
      const int w = wbase + mt * 16 + l15;
#pragma unroll
      for (int ct = 0; ct < 4; ++ct)
#pragma unroll
        for (int r = 0; r < 4; ++r) {
          const int co = co0 + ct * 16 + l4 * 4 + r;
          of32[(((size_t)b * COUT + co) * Hc + h) * Wc + w] = acc[mt][ct][r];
        }
    }
  }
}

// ---------------- CPB relative-position bias: 81 entries x 8 heads ----------------
__global__ __launch_bounds__(64)
void cpb_bias_kernel(const float* __restrict__ w1, const float* __restrict__ b1,
                     const float* __restrict__ w2, float* __restrict__ biasf) {
  const int e = blockIdx.x;
  const int d0 = e / 9, d1 = e % 9;
  const int r0 = d0 - 4, r1 = d1 - 4;
  float t0 = log2f(fabsf((float)r0) * 2.0f + 1.0f) * (1.0f / 3.0f); if (r0 < 0) t0 = -t0;
  float t1 = log2f(fabsf((float)r1) * 2.0f + 1.0f) * (1.0f / 3.0f); if (r1 < 0) t1 = -t1;
  const int lane = threadIdx.x;
  float acc[8];
#pragma unroll
  for (int n = 0; n < 8; ++n) acc[n] = 0.f;
  for (int k = lane; k < 512; k += 64) {
    float hk = fmaf(t0, w1[k * 2 + 0], fmaf(t1, w1[k * 2 + 1], b1[k]));
    hk = fmaxf(hk, 0.f);
#pragma unroll
    for (int n = 0; n < 8; ++n) acc[n] = fmaf(hk, w2[n * 512 + k], acc[n]);
  }
#pragma unroll
  for (int n = 0; n < 8; ++n) {
#pragma unroll
    for (int off = 32; off > 0; off >>= 1) acc[n] += __shfl_xor(acc[n], off, 64);
  }
  if (lane == 0) {
#pragma unroll
    for (int n = 0; n < 8; ++n)
      biasf[e * 8 + n] = 16.0f / (1.0f + expf(-acc[n]));
  }
}

// ---------------- 5x5 window cosine attention (optionally shifted) ----------------
// reads xq NHWC bf16 [B][160][160][384]; writes ypad interior channels [y_ch_off, +64)
__global__ __launch_bounds__(256)
void win_attn_kernel(const unsigned short* __restrict__ xq, const float* __restrict__ biasf,
                     const float* __restrict__ logit_scale, unsigned short* __restrict__ ypad,
                     int chan_off, int y_ch_off, int shift_in, int shift_out) {
  __shared__ f32x4 kn4[8][25][2];
  __shared__ f32x4 vv4[8][25][2];
  const int head = threadIdx.x >> 5;
  const int i = threadIdx.x & 31;
  int blk = blockIdx.x;
  const int wb_i = blk % 32; blk /= 32;
  const int hb_i = blk % 32; blk /= 32;
  const int b = blk;
  const int wi = i / 5, wj = i % 5;
  const int gh = hb_i * 5 + wi, gw = wb_i * 5 + wj;
  const int sh = (gh + shift_in) % Hc, sw = (gw + shift_in) % Wc;

  if (i < 25) {
    const unsigned short* base = xq + (((size_t)b * Hc + sh) * Wc + sw) * 384 + chan_off + head * 8;
    short8 kv = *(const short8*)base;
    short8 vv = *(const short8*)(base + 64);
    float k[8]; float nrm = 0.f;
#pragma unroll
    for (int c = 0; c < 8; ++c) { k[c] = bf2f((unsigned short)kv[c]); nrm = fmaf(k[c], k[c], nrm); }
    const float inv = 1.0f / fmaxf(sqrtf(nrm), 1e-12f);
    f32x4 a0, a1, b0, b1;
#pragma unroll
    for (int c = 0; c < 4; ++c) { a0[c] = k[c] * inv; a1[c] = k[c + 4] * inv; }
#pragma unroll
    for (int c = 0; c < 4; ++c) { b0[c] = bf2f((unsigned short)vv[c]); b1[c] = bf2f((unsigned short)vv[c + 4]); }
    kn4[head][i][0] = a0; kn4[head][i][1] = a1;
    vv4[head][i][0] = b0; vv4[head][i][1] = b1;
  }
  __syncthreads();
  if (i >= 25) return;

  const float scale = expf(fminf(logit_scale[head], 4.6051702f));
  const f32x4 q0 = kn4[head][i][0], q1 = kn4[head][i][1];
  float s[25];
#pragma unroll
  for (int j = 0; j < 25; ++j) {
    const float d = dot8(q0, q1, kn4[head][j][0], kn4[head][j][1]);
    const int d0 = wi - (j / 5) + 4, d1 = wj - (j % 5) + 4;
    s[j] = fmaf(d, scale, biasf[(d0 * 9 + d1) * 8 + head]);
  }
  float m = -1e30f;
#pragma unroll
  for (int j = 0; j < 25; ++j) m = fmaxf(m, s[j]);
  float den = 0.f;
  f32x4 acc0 = {0.f, 0.f, 0.f, 0.f}, acc1 = {0.f, 0.f, 0.f, 0.f};
#pragma unroll
  for (int j = 0; j < 25; ++j) {
    const float p = __expf(s[j] - m);
    den += p;
    acc0 += vv4[head][j][0] * p;
    acc1 += vv4[head][j][1] * p;
  }
  const float rden = 1.0f / den;
  const int oh = (gh + shift_out) % Hc, ow = (gw + shift_out) % Wc;
  short8 o;
#pragma unroll
  for (int c = 0; c < 4; ++c) { o[c] = (short)f2bf(acc0[c] * rden); o[c + 4] = (short)f2bf(acc1[c] * rden); }
  *(short8*)(ypad + (((size_t)b * HP + oh + 1) * HP + ow + 1) * 192 + y_ch_off + head * 8) = o;
}

// ---------------- axial row pass -> vrow bf16 [b][head][h][w][8] ----------------
// cosine attn: max logit is exactly scale (at j=i) -> single pass, m=scale.
__global__ __launch_bounds__(192)
void row_attn_kernel(const unsigned short* __restrict__ xq, const float* __restrict__ lrs,
                     unsigned short* __restrict__ vrow) {
  __shared__ f32x4 kn4[160][2];
  __shared__ f32x4 vv4[160][2];
  int blk = blockIdx.x;
  const int head = blk % 8; blk /= 8;
  const int h = blk % 160; blk /= 160;
  const int b = blk;
  const int i = threadIdx.x;

  if (i < 160) {
    const unsigned short* base = xq + (((size_t)b * Hc + h) * Wc + i) * 384 + 256 + head * 8;
    short8 kv = *(const short8*)base;
    short8 vv = *(const short8*)(base + 64);
    float k[8]; float nrm = 0.f;
#pragma unroll
    for (int c = 0; c < 8; ++c) { k[c] = bf2f((unsigned short)kv[c]); nrm = fmaf(k[c], k[c], nrm); }
    const float inv = 1.0f / fmaxf(sqrtf(nrm), 1e-12f);
    f32x4 a0, a1, b0, b1;
#pragma unroll
    for (int c = 0; c < 4; ++c) { a0[c] = k[c] * inv; a1[c] = k[c + 4] * inv; }
#pragma unroll
    for (int c = 0; c < 4; ++c) { b0[c] = bf2f((unsigned short)vv[c]); b1[c] = bf2f((unsigned short)vv[c + 4]); }
    kn4[i][0] = a0; kn4[i][1] = a1;
    vv4[i][0] = b0; vv4[i][1] = b1;
  }
  __syncthreads();
  if (i >= 160) return;

  const float scale = expf(fminf(lrs[head], 4.6051702f));
  const f32x4 q0 = kn4[i][0], q1 = kn4[i][1];
  float den = 0.f;
  f32x4 acc0 = {0.f, 0.f, 0.f, 0.f}, acc1 = {0.f, 0.f, 0.f, 0.f};
  for (int j = 0; j < 160; ++j) {
    const float d = dot8(q0, q1, kn4[j][0], kn4[j][1]);
    const float p = __expf(fmaf(d, scale, -scale));
    den += p;
    acc0 += vv4[j][0] * p;
    acc1 += vv4[j][1] * p;
  }
  const float rden = 1.0f / den;
  short8 o;
#pragma unroll
  for (int c = 0; c < 4; ++c) { o[c] = (short)f2bf(acc0[c] * rden); o[c + 4] = (short)f2bf(acc1[c] * rden); }
  *(short8*)(vrow + ((((size_t)b * 8 + head) * 160 + h) * 160 + i) * 8) = o;
}

// ---------------- axial column pass -> ypad channels 128..191 ----------------
__global__ __launch_bounds__(192)
void col_attn_kernel(const unsigned short* __restrict__ xq, const float* __restrict__ lrs,
                     const unsigned short* __restrict__ vrow, unsigned short* __restrict__ ypad) {
  __shared__ f32x4 kn4[160][2];
  __shared__ f32x4 vv4[160][2];
  int blk = blockIdx.x;
  const int head = blk % 8; blk /= 8;
  const int w = blk % 160; blk /= 160;
  const int b = blk;
  const int i = threadIdx.x;

  if (i < 160) {
    const unsigned short* kb = xq + (((size_t)b * Hc + i) * Wc + w) * 384 + 256 + head * 8;
    short8 kv = *(const short8*)kb;
    short8 vv = *(const short8*)(vrow + ((((size_t)b * 8 + head) * 160 + i) * 160 + w) * 8);
    float k[8]; float nrm = 0.f;
#pragma unroll
    for (int c = 0; c < 8; ++c) { k[c] = bf2f((unsigned short)kv[c]); nrm = fmaf(k[c], k[c], nrm); }
    const float inv = 1.0f / fmaxf(sqrtf(nrm), 1e-12f);
    f32x4 a0, a1, b0, b1;
#pragma unroll
    for (int c = 0; c < 4; ++c) { a0[c] = k[c] * inv; a1[c] = k[c + 4] * inv; }
#pragma unroll
    for (int c = 0; c < 4; ++c) { b0[c] = bf2f((unsigned short)vv[c]); b1[c] = bf2f((unsigned short)vv[c + 4]); }
    kn4[i][0] = a0; kn4[i][1] = a1;
    vv4[i][0] = b0; vv4[i][1] = b1;
  }
  __syncthreads();
  if (i >= 160) return;

  const float scale = expf(fminf(lrs[head], 4.6051702f));
  const f32x4 q0 = kn4[i][0], q1 = kn4[i][1];
  float den = 0.f;
  f32x4 acc0 = {0.f, 0.f, 0.f, 0.f}, acc1 = {0.f, 0.f, 0.f, 0.f};
  for (int j = 0; j < 160; ++j) {
    const float d = dot8(q0, q1, kn4[j][0], kn4[j][1]);
    const float p = __expf(fmaf(d, scale, -scale));
    den += p;
    acc0 += vv4[j][0] * p;
    acc1 += vv4[j][1] * p;
  }
  const float rden = 1.0f / den;
  short8 o;
#pragma unroll
  for (int c = 0; c < 4; ++c) { o[c] = (short)f2bf(acc0[c] * rden); o[c + 4] = (short)f2bf(acc1[c] * rden); }
  *(short8*)(ypad + (((size_t)b * HP + i + 1) * HP + w + 1) * 192 + 128 + head * 8) = o;
}

extern "C" void kernel_launch(void* const* d_in, const int* in_sizes, int n_in,
                              void* d_out, int out_size, void* d_ws, size_t ws_size,
                              hipStream_t stream) {
  const float* x     = (const float*)d_in[0];
  const float* w_in  = (const float*)d_in[1];
  const float* b_in  = (const float*)d_in[2];
  const float* w_out = (const float*)d_in[3];
  const float* b_out = (const float*)d_in[4];
  const float* ls    = (const float*)d_in[5];
  const float* lrs   = (const float*)d_in[6];
  const float* cw1   = (const float*)d_in[7];
  const float* cb1   = (const float*)d_in[8];
  const float* cw2   = (const float*)d_in[9];
  float* out = (float*)d_out;

  // workspace layout (xpad and ypad adjacent for joint zeroing)
  char* p = (char*)d_ws;
  unsigned short* xpad = (unsigned short*)p;  p += (size_t)Bc * HP * HP * 192 * 2;   // 20.16 MB
  unsigned short* ypad = (unsigned short*)p;  p += (size_t)Bc * HP * HP * 192 * 2;   // 20.16 MB
  unsigned short* xq   = (unsigned short*)p;  p += (size_t)Bc * Hc * Wc * 384 * 2;   // 39.32 MB
  unsigned short* vrow = (unsigned short*)p;  p += (size_t)Bc * 8 * Hc * Wc * 8 * 2; //  6.55 MB
  unsigned short* wtr1 = (unsigned short*)p;  p += (size_t)9 * 384 * 192 * 2;        //  1.33 MB
  unsigned short* wtr2 = (unsigned short*)p;  p += (size_t)9 * 192 * 192 * 2;        //  0.66 MB
  float* biasf = (float*)p;

  const long padChunks = (long)Bc * HP * HP * 192 * 2 * 2 / 16;  // xpad+ypad, 16B chunks
  zero16<<<2048, 256, 0, stream>>>(xpad, padChunks);
  nchw2nhwc_pad<<<Bc * 160 * 5, 256, 0, stream>>>(x, xpad);
  wtransform<<<(384 * 192 + 255) / 256, 256, 0, stream>>>(w_in, wtr1, 384, 192);
  wtransform<<<(192 * 192 + 255) / 256, 256, 0, stream>>>(w_out, wtr2, 192, 192);
  cpb_bias_kernel<<<81, 64, 0, stream>>>(cw1, cb1, cw2, biasf);
  // conv_in 192->384 (BH=2, 4 waves)
  conv_mfma<192, 384, 2, 0><<<dim3(80, 6, Bc), 256, 0, stream>>>(xpad, wtr1, b_in, xq, nullptr);
  // attention branches (write ypad interior)
  win_attn_kernel<<<Bc * 32 * 32, 256, 0, stream>>>(xq, biasf, ls, ypad, 0, 0, 0, 0);
  win_attn_kernel<<<Bc * 32 * 32, 256, 0, stream>>>(xq, biasf, ls, ypad, 128, 64, 3, 2);
  row_attn_kernel<<<Bc * 160 * 8, 192, 0, stream>>>(xq, lrs, vrow);
  col_attn_kernel<<<Bc * 160 * 8, 192, 0, stream>>>(xq, lrs, vrow, ypad);
  // conv_out 192->192 (BH=1, 2 waves)
  conv_mfma<192, 192, 1, 1><<<dim3(160, 3, Bc), 128, 0, stream>>>(ypad, wtr2, b_out, nullptr, out);
}

// Round 4
// 349.156 us; speedup vs baseline: 6.4885x; 1.0247x over previous
//
#include <hip/hip_runtime.h>
#include <math.h>

// GeoAB: conv3x3(192->384, bf16 MFMA) -> [win attn fused | axial attn] -> conv3x3(192->192, bf16 MFMA)
// B=2, H=W=160, WS=5, NH=8, CPH=8.

typedef __attribute__((ext_vector_type(8))) short short8;
typedef __attribute__((ext_vector_type(4))) short short4v;
typedef __attribute__((ext_vector_type(4))) float f32x4;

constexpr int Hc = 160, Wc = 160, Bc = 2;
constexpr int HPR = 162;   // padded rows
constexpr int HPW = 164;   // padded cols (extra 2 for slab alignment)

__device__ inline unsigned short f2bf(float f) {
  union { float f; unsigned u; } v; v.f = f;
  unsigned r = v.u + 0x7FFF + ((v.u >> 16) & 1);
  return (unsigned short)(r >> 16);
}
__device__ inline float bf2f(unsigned short h) {
  union { unsigned u; float f; } v; v.u = ((unsigned)h) << 16;
  return v.f;
}

__device__ inline void gl16(const void* g, void* l) {
  __builtin_amdgcn_global_load_lds((const __attribute__((address_space(1))) unsigned int*)g,
                                   (__attribute__((address_space(3))) unsigned int*)l, 16, 0, 0);
}

__device__ inline float dot8(f32x4 a0, f32x4 a1, f32x4 b0, f32x4 b1) {
  float d = a0[0] * b0[0];
  d = fmaf(a0[1], b0[1], d); d = fmaf(a0[2], b0[2], d); d = fmaf(a0[3], b0[3], d);
  d = fmaf(a1[0], b1[0], d); d = fmaf(a1[1], b1[1], d);
  d = fmaf(a1[2], b1[2], d); d = fmaf(a1[3], b1[3], d);
  return d;
}

// ---------------- zero only the borders of xpad/ypad ----------------
// positions: rows {0,161} x cols [0,164)  (328) + rows [1,161) x cols {0,161,162,163} (640) = 968
__global__ __launch_bounds__(256)
void zero_borders(unsigned short* __restrict__ xpad, unsigned short* __restrict__ ypad) {
  const int NPOS = 968;
  const int total = 2 * 2 * NPOS * 24;   // buf, b, pos, 24 chunks of 8ch
  int idx = blockIdx.x * 256 + threadIdx.x;
  if (idx >= total) return;
  const int ch = idx % 24; int q = idx / 24;
  const int pos = q % NPOS; q /= NPOS;
  const int b = q & 1; const int buf = q >> 1;
  int row, col;
  if (pos < 328) { row = (pos < 164) ? 0 : 161; col = pos % 164; }
  else { int r = pos - 328; row = 1 + (r >> 2); int cm = r & 3; col = cm == 0 ? 0 : 160 + cm; }
  unsigned short* p = (buf ? ypad : xpad) + (((size_t)b * HPR + row) * HPW + col) * 192 + ch * 8;
  short8 z = {};
  *(short8*)p = z;
}

// ---------------- NCHW fp32 -> padded NHWC bf16 ----------------
__global__ __launch_bounds__(256)
void nchw2nhwc_pad(const float* __restrict__ x, unsigned short* __restrict__ xpad) {
  __shared__ float tile[192][33];
  int blk = blockIdx.x;
  const int w0 = (blk % 5) * 32; blk /= 5;
  const int h = blk % 160;
  const int b = blk / 160;
  const int t = threadIdx.x;
  for (int i = t; i < 192 * 32; i += 256) {
    int c = i >> 5, w = i & 31;
    tile[c][w] = x[(((size_t)b * 192 + c) * 160 + h) * 160 + w0 + w];
  }
  __syncthreads();
  for (int i = t; i < 32 * 192; i += 256) {
    int w = i / 192, c = i % 192;
    xpad[(((size_t)b * HPR + h + 1) * HPW + w0 + w + 1) * 192 + c] = f2bf(tile[c][w]);
  }
}

// ---------------- weights OIHW fp32 -> [tap][co][ci] bf16 ----------------
__global__ __launch_bounds__(256)
void wtransform(const float* __restrict__ w, unsigned short* __restrict__ wtr, int CO, int CI) {
  int id = blockIdx.x * 256 + threadIdx.x;
  if (id >= CO * CI) return;
  const float* wp = w + (size_t)id * 9;
#pragma unroll
  for (int tap = 0; tap < 9; ++tap)
    wtr[(size_t)tap * CO * CI + id] = f2bf(wp[tap]);
}

// ---------------- conv3x3 SAME, implicit GEMM, bf16 MFMA ----------------
// xin: padded NHWC bf16 [B][162][164][192]; wtr: [9][COUT][192] bf16.
// Block covers BH h-rows x 80 w x 64 co. Waves: wid -> (hr = wid/NWC, wc = wid%NWC).
// Wave tile: 80 w (5 mt) x CT*16 co. Slab: [R=BH+2][84 cols][32 ch], chunk-swizzled.
template<int COUT, int BH, int NWC, int CT, int OUTMODE, int MINW>
__global__ __launch_bounds__(64 * BH * NWC, MINW)
void conv_mfma(const unsigned short* __restrict__ xin, const unsigned short* __restrict__ wtr,
               const float* __restrict__ bias, unsigned short* __restrict__ obf,
               float* __restrict__ of32) {
  constexpr int CIN = 192;
  constexpr int WAVES = BH * NWC;
  constexpr int R = BH + 2;
  constexpr int TOTAL = R * 84 * 4;     // 16B chunks per K-step
  __shared__ unsigned short slab[R * 84 * 32];
  const int t = threadIdx.x, lane = t & 63, wid = t >> 6;
  const int bx = blockIdx.x, cog = blockIdx.y, b = blockIdx.z;
  const int ws = bx & 1, hb = bx >> 1;
  const int w0 = ws * 80, h0 = hb * BH;
  const int hr = wid / NWC, wc = wid % NWC;
  const int l15 = lane & 15, l4 = lane >> 4;
  const int co0 = cog * 64 + wc * (CT * 16);

  f32x4 acc[5][CT];
#pragma unroll
  for (int ct = 0; ct < CT; ++ct) {
    f32x4 bi;
#pragma unroll
    for (int r = 0; r < 4; ++r) bi[r] = bias[co0 + ct * 16 + l4 * 4 + r];
#pragma unroll
    for (int mt = 0; mt < 5; ++mt) acc[mt][ct] = bi;
  }

  for (int cs = 0; cs < 6; ++cs) {
    // ---- stage x slab via global_load_lds (source chunk-swizzled, dest linear) ----
    for (int ib = wid; ib * 64 < TOTAL; ib += WAVES) {
      const int n = ib * 64 + lane;
      if (n < TOTAL) {
        const int c = n & 3, q = n >> 2;
        const int r = q / 84, wv = q - r * 84;
        const int csrc = c ^ ((wv >> 1) & 3);
        const unsigned short* g = xin +
            (((size_t)b * HPR + h0 + r) * HPW + w0 + wv) * CIN + cs * 32 + csrc * 8;
        gl16(g, &slab[ib * 512]);
      }
    }
    __syncthreads();
#pragma unroll
    for (int ky = 0; ky < 3; ++ky) {
      short8 a[3][CT];
#pragma unroll
      for (int kx = 0; kx < 3; ++kx)
#pragma unroll
        for (int ct = 0; ct < CT; ++ct)
          a[kx][ct] = *(const short8*)(wtr +
              ((size_t)(ky * 3 + kx) * COUT + co0 + ct * 16 + l15) * CIN + cs * 32 + l4 * 8);
      const unsigned short* srow = &slab[(hr + ky) * 84 * 32];
#pragma unroll
      for (int kx = 0; kx < 3; ++kx) {
#pragma unroll
        for (int mt = 0; mt < 5; ++mt) {
          const int wv = mt * 16 + l15 + kx;
          const int cr = l4 ^ ((wv >> 1) & 3);
          short8 bf = *(const short8*)(srow + wv * 32 + cr * 8);
#pragma unroll
          for (int ct = 0; ct < CT; ++ct)
            acc[mt][ct] = __builtin_amdgcn_mfma_f32_16x16x32_bf16(a[kx][ct], bf, acc[mt][ct], 0, 0, 0);
        }
      }
    }
    __syncthreads();
  }
  // ---- epilogue: D row = co (l4*4+r), col = w (l15) ----
  const int h = h0 + hr;
  if (OUTMODE == 0) {
#pragma unroll
    for (int mt = 0; mt < 5; ++mt) {
      const int w = w0 + mt * 16 + l15;
      unsigned short* dst0 = obf + (((size_t)b * Hc + h) * Wc + w) * 384 + co0 + l4 * 4;
#pragma unroll
      for (int ct = 0; ct < CT; ++ct) {
        short4v s;
#pragma unroll
        for (int r = 0; r < 4; ++r) s[r] = (short)f2bf(acc[mt][ct][r]);
        *(short4v*)(dst0 + ct * 16) = s;
      }
    }
  } else {
#pragma unroll
    for (int mt = 0; mt < 5; ++mt) {
      const int w = w0 + mt * 16 + l15;
#pragma unroll
      for (int ct = 0; ct < CT; ++ct)
#pragma unroll
        for (int r = 0; r < 4; ++r) {
          const int co = co0 + ct * 16 + l4 * 4 + r;
          of32[(((size_t)b * COUT + co) * Hc + h) * Wc + w] = acc[mt][ct][r];
        }
    }
  }
}

// ---------------- CPB relative-position bias: 81 entries x 8 heads ----------------
__global__ __launch_bounds__(64)
void cpb_bias_kernel(const float* __restrict__ w1, const float* __restrict__ b1,
                     const float* __restrict__ w2, float* __restrict__ biasf) {
  const int e = blockIdx.x;
  const int d0 = e / 9, d1 = e % 9;
  const int r0 = d0 - 4, r1 = d1 - 4;
  float t0 = log2f(fabsf((float)r0) * 2.0f + 1.0f) * (1.0f / 3.0f); if (r0 < 0) t0 = -t0;
  float t1 = log2f(fabsf((float)r1) * 2.0f + 1.0f) * (1.0f / 3.0f); if (r1 < 0) t1 = -t1;
  const int lane = threadIdx.x;
  float acc[8];
#pragma unroll
  for (int n = 0; n < 8; ++n) acc[n] = 0.f;
  for (int k = lane; k < 512; k += 64) {
    float hk = fmaf(t0, w1[k * 2 + 0], fmaf(t1, w1[k * 2 + 1], b1[k]));
    hk = fmaxf(hk, 0.f);
#pragma unroll
    for (int n = 0; n < 8; ++n) acc[n] = fmaf(hk, w2[n * 512 + k], acc[n]);
  }
#pragma unroll
  for (int n = 0; n < 8; ++n) {
#pragma unroll
    for (int off = 32; off > 0; off >>= 1) acc[n] += __shfl_xor(acc[n], off, 64);
  }
  if (lane == 0) {
#pragma unroll
    for (int n = 0; n < 8; ++n)
      biasf[e * 8 + n] = 16.0f / (1.0f + expf(-acc[n]));
  }
}

// ---------------- 5x5 window cosine attention (both variants fused) ----------------
// reads xq NHWC bf16 [B][160][160][384]; writes ypad interior channels [y_ch_off, +64)
__global__ __launch_bounds__(256)
void win_attn_kernel(const unsigned short* __restrict__ xq, const float* __restrict__ biasf,
                     const float* __restrict__ logit_scale, unsigned short* __restrict__ ypad) {
  __shared__ f32x4 kn4[8][25][2];
  __shared__ f32x4 vv4[8][25][2];
  const int head = threadIdx.x >> 5;
  const int i = threadIdx.x & 31;
  const int variant = blockIdx.y;
  const int chan_off = variant ? 128 : 0;
  const int y_ch_off = variant ? 64 : 0;
  const int shift_in = variant ? 3 : 0;
  const int shift_out = variant ? 2 : 0;
  int blk = blockIdx.x;
  const int wb_i = blk % 32; blk /= 32;
  const int hb_i = blk;
  const int b = blockIdx.z;
  const int wi = i / 5, wj = i % 5;
  const int gh = hb_i * 5 + wi, gw = wb_i * 5 + wj;
  const int sh = (gh + shift_in) % Hc, sw = (gw + shift_in) % Wc;

  if (i < 25) {
    const unsigned short* base = xq + (((size_t)b * Hc + sh) * Wc + sw) * 384 + chan_off + head * 8;
    short8 kv = *(const short8*)base;
    short8 vv = *(const short8*)(base + 64);
    float k[8]; float nrm = 0.f;
#pragma unroll
    for (int c = 0; c < 8; ++c) { k[c] = bf2f((unsigned short)kv[c]); nrm = fmaf(k[c], k[c], nrm); }
    const float inv = 1.0f / fmaxf(sqrtf(nrm), 1e-12f);
    f32x4 a0, a1, b0, b1;
#pragma unroll
    for (int c = 0; c < 4; ++c) { a0[c] = k[c] * inv; a1[c] = k[c + 4] * inv; }
#pragma unroll
    for (int c = 0; c < 4; ++c) { b0[c] = bf2f((unsigned short)vv[c]); b1[c] = bf2f((unsigned short)vv[c + 4]); }
    kn4[head][i][0] = a0; kn4[head][i][1] = a1;
    vv4[head][i][0] = b0; vv4[head][i][1] = b1;
  }
  __syncthreads();
  if (i >= 25) return;

  const float scale = expf(fminf(logit_scale[head], 4.6051702f));
  const f32x4 q0 = kn4[head][i][0], q1 = kn4[head][i][1];
  float s[25];
#pragma unroll
  for (int j = 0; j < 25; ++j) {
    const float d = dot8(q0, q1, kn4[head][j][0], kn4[head][j][1]);
    const int d0 = wi - (j / 5) + 4, d1 = wj - (j % 5) + 4;
    s[j] = fmaf(d, scale, biasf[(d0 * 9 + d1) * 8 + head]);
  }
  float m = -1e30f;
#pragma unroll
  for (int j = 0; j < 25; ++j) m = fmaxf(m, s[j]);
  float den = 0.f;
  f32x4 acc0 = {0.f, 0.f, 0.f, 0.f}, acc1 = {0.f, 0.f, 0.f, 0.f};
#pragma unroll
  for (int j = 0; j < 25; ++j) {
    const float p = __expf(s[j] - m);
    den += p;
    acc0 += vv4[head][j][0] * p;
    acc1 += vv4[head][j][1] * p;
  }
  const float rden = 1.0f / den;
  const int oh = (gh + shift_out) % Hc, ow = (gw + shift_out) % Wc;
  short8 o;
#pragma unroll
  for (int c = 0; c < 4; ++c) { o[c] = (short)f2bf(acc0[c] * rden); o[c + 4] = (short)f2bf(acc1[c] * rden); }
  *(short8*)(ypad + (((size_t)b * HPR + oh + 1) * HPW + ow + 1) * 192 + y_ch_off + head * 8) = o;
}

// ---------------- axial row pass -> vrow bf16 [b][head][h][w][8] ----------------
__global__ __launch_bounds__(192)
void row_attn_kernel(const unsigned short* __restrict__ xq, const float* __restrict__ lrs,
                     unsigned short* __restrict__ vrow) {
  __shared__ f32x4 kn4[160][2];
  __shared__ f32x4 vv4[160][2];
  int blk = blockIdx.x;
  const int head = blk % 8; blk /= 8;
  const int h = blk % 160; blk /= 160;
  const int b = blk;
  const int i = threadIdx.x;

  if (i < 160) {
    const unsigned short* base = xq + (((size_t)b * Hc + h) * Wc + i) * 384 + 256 + head * 8;
    short8 kv = *(const short8*)base;
    short8 vv = *(const short8*)(base + 64);
    float k[8]; float nrm = 0.f;
#pragma unroll
    for (int c = 0; c < 8; ++c) { k[c] = bf2f((unsigned short)kv[c]); nrm = fmaf(k[c], k[c], nrm); }
    const float inv = 1.0f / fmaxf(sqrtf(nrm), 1e-12f);
    f32x4 a0, a1, b0, b1;
#pragma unroll
    for (int c = 0; c < 4; ++c) { a0[c] = k[c] * inv; a1[c] = k[c + 4] * inv; }
#pragma unroll
    for (int c = 0; c < 4; ++c) { b0[c] = bf2f((unsigned short)vv[c]); b1[c] = bf2f((unsigned short)vv[c + 4]); }
    kn4[i][0] = a0; kn4[i][1] = a1;
    vv4[i][0] = b0; vv4[i][1] = b1;
  }
  __syncthreads();
  if (i >= 160) return;

  const float scale = expf(fminf(lrs[head], 4.6051702f));
  const f32x4 q0 = kn4[i][0], q1 = kn4[i][1];
  float den = 0.f;
  f32x4 acc0 = {0.f, 0.f, 0.f, 0.f}, acc1 = {0.f, 0.f, 0.f, 0.f};
  for (int j = 0; j < 160; ++j) {
    const float d = dot8(q0, q1, kn4[j][0], kn4[j][1]);
    const float p = __expf(fmaf(d, scale, -scale));
    den += p;
    acc0 += vv4[j][0] * p;
    acc1 += vv4[j][1] * p;
  }
  const float rden = 1.0f / den;
  short8 o;
#pragma unroll
  for (int c = 0; c < 4; ++c) { o[c] = (short)f2bf(acc0[c] * rden); o[c + 4] = (short)f2bf(acc1[c] * rden); }
  *(short8*)(vrow + ((((size_t)b * 8 + head) * 160 + h) * 160 + i) * 8) = o;
}

// ---------------- axial column pass -> ypad channels 128..191 ----------------
__global__ __launch_bounds__(192)
void col_attn_kernel(const unsigned short* __restrict__ xq, const float* __restrict__ lrs,
                     const unsigned short* __restrict__ vrow, unsigned short* __restrict__ ypad) {
  __shared__ f32x4 kn4[160][2];
  __shared__ f32x4 vv4[160][2];
  int blk = blockIdx.x;
  const int head = blk % 8; blk /= 8;
  const int w = blk % 160; blk /= 160;
  const int b = blk;
  const int i = threadIdx.x;

  if (i < 160) {
    const unsigned short* kb = xq + (((size_t)b * Hc + i) * Wc + w) * 384 + 256 + head * 8;
    short8 kv = *(const short8*)kb;
    short8 vv = *(const short8*)(vrow + ((((size_t)b * 8 + head) * 160 + i) * 160 + w) * 8);
    float k[8]; float nrm = 0.f;
#pragma unroll
    for (int c = 0; c < 8; ++c) { k[c] = bf2f((unsigned short)kv[c]); nrm = fmaf(k[c], k[c], nrm); }
    const float inv = 1.0f / fmaxf(sqrtf(nrm), 1e-12f);
    f32x4 a0, a1, b0, b1;
#pragma unroll
    for (int c = 0; c < 4; ++c) { a0[c] = k[c] * inv; a1[c] = k[c + 4] * inv; }
#pragma unroll
    for (int c = 0; c < 4; ++c) { b0[c] = bf2f((unsigned short)vv[c]); b1[c] = bf2f((unsigned short)vv[c + 4]); }
    kn4[i][0] = a0; kn4[i][1] = a1;
    vv4[i][0] = b0; vv4[i][1] = b1;
  }
  __syncthreads();
  if (i >= 160) return;

  const float scale = expf(fminf(lrs[head], 4.6051702f));
  const f32x4 q0 = kn4[i][0], q1 = kn4[i][1];
  float den = 0.f;
  f32x4 acc0 = {0.f, 0.f, 0.f, 0.f}, acc1 = {0.f, 0.f, 0.f, 0.f};
  for (int j = 0; j < 160; ++j) {
    const float d = dot8(q0, q1, kn4[j][0], kn4[j][1]);
    const float p = __expf(fmaf(d, scale, -scale));
    den += p;
    acc0 += vv4[j][0] * p;
    acc1 += vv4[j][1] * p;
  }
  const float rden = 1.0f / den;
  short8 o;
#pragma unroll
  for (int c = 0; c < 4; ++c) { o[c] = (short)f2bf(acc0[c] * rden); o[c + 4] = (short)f2bf(acc1[c] * rden); }
  *(short8*)(ypad + (((size_t)b * HPR + i + 1) * HPW + w + 1) * 192 + 128 + head * 8) = o;
}

extern "C" void kernel_launch(void* const* d_in, const int* in_sizes, int n_in,
                              void* d_out, int out_size, void* d_ws, size_t ws_size,
                              hipStream_t stream) {
  const float* x     = (const float*)d_in[0];
  const float* w_in  = (const float*)d_in[1];
  const float* b_in  = (const float*)d_in[2];
  const float* w_out = (const float*)d_in[3];
  const float* b_out = (const float*)d_in[4];
  const float* ls    = (const float*)d_in[5];
  const float* lrs   = (const float*)d_in[6];
  const float* cw1   = (const float*)d_in[7];
  const float* cb1   = (const float*)d_in[8];
  const float* cw2   = (const float*)d_in[9];
  float* out = (float*)d_out;

  // workspace layout
  char* p = (char*)d_ws;
  unsigned short* xpad = (unsigned short*)p;  p += (size_t)Bc * HPR * HPW * 192 * 2;   // 20.4 MB
  unsigned short* ypad = (unsigned short*)p;  p += (size_t)Bc * HPR * HPW * 192 * 2;   // 20.4 MB
  unsigned short* xq   = (unsigned short*)p;  p += (size_t)Bc * Hc * Wc * 384 * 2;     // 39.3 MB
  unsigned short* vrow = (unsigned short*)p;  p += (size_t)Bc * 8 * Hc * Wc * 8 * 2;   //  6.6 MB
  unsigned short* wtr1 = (unsigned short*)p;  p += (size_t)9 * 384 * 192 * 2;          //  1.3 MB
  unsigned short* wtr2 = (unsigned short*)p;  p += (size_t)9 * 192 * 192 * 2;          //  0.7 MB
  float* biasf = (float*)p;

  zero_borders<<<(2 * 2 * 968 * 24 + 255) / 256, 256, 0, stream>>>(xpad, ypad);
  nchw2nhwc_pad<<<Bc * 160 * 5, 256, 0, stream>>>(x, xpad);
  wtransform<<<(384 * 192 + 255) / 256, 256, 0, stream>>>(w_in, wtr1, 384, 192);
  wtransform<<<(192 * 192 + 255) / 256, 256, 0, stream>>>(w_out, wtr2, 192, 192);
  cpb_bias_kernel<<<81, 64, 0, stream>>>(cw1, cb1, cw2, biasf);
  // conv_in 192->384: BH=4, waves=4 (1 per h-row), 64co/wave
  conv_mfma<384, 4, 1, 4, 0, 3><<<dim3(80, 6, Bc), 256, 0, stream>>>(xpad, wtr1, b_in, xq, nullptr);
  // attention branches (write ypad interior)
  win_attn_kernel<<<dim3(1024, 2, Bc), 256, 0, stream>>>(xq, biasf, ls, ypad);
  row_attn_kernel<<<Bc * 160 * 8, 192, 0, stream>>>(xq, lrs, vrow);
  col_attn_kernel<<<Bc * 160 * 8, 192, 0, stream>>>(xq, lrs, vrow, ypad);
  // conv_out 192->192: BH=2, waves=4 (2h x 2co), 32co/wave
  conv_mfma<192, 2, 2, 2, 1, 4><<<dim3(160, 3, Bc), 256, 0, stream>>>(ypad, wtr2, b_out, nullptr, out);
}

// Round 5
// 315.989 us; speedup vs baseline: 7.1696x; 1.1050x over previous
//
#include <hip/hip_runtime.h>
#include <math.h>

// GeoAB: conv3x3(192->384, bf16 MFMA, 2-phase pipelined) -> [win attn fused | axial attn]
//        -> conv3x3(192->192, bf16 MFMA).  B=2, H=W=160, WS=5, NH=8, CPH=8.

typedef __attribute__((ext_vector_type(8))) short short8;
typedef __attribute__((ext_vector_type(4))) short short4v;
typedef __attribute__((ext_vector_type(4))) float f32x4;

constexpr int Hc = 160, Wc = 160, Bc = 2;
constexpr int HPR = 162;   // padded rows
constexpr int HPW = 164;   // padded cols

__device__ inline unsigned short f2bf(float f) {
  union { float f; unsigned u; } v; v.f = f;
  unsigned r = v.u + 0x7FFF + ((v.u >> 16) & 1);
  return (unsigned short)(r >> 16);
}
__device__ inline float bf2f(unsigned short h) {
  union { unsigned u; float f; } v; v.u = ((unsigned)h) << 16;
  return v.f;
}

__device__ inline void gl16(const void* g, void* l) {
  __builtin_amdgcn_global_load_lds((const __attribute__((address_space(1))) unsigned int*)g,
                                   (__attribute__((address_space(3))) unsigned int*)l, 16, 0, 0);
}

__device__ inline float dot8(f32x4 a0, f32x4 a1, f32x4 b0, f32x4 b1) {
  float d = a0[0] * b0[0];
  d = fmaf(a0[1], b0[1], d); d = fmaf(a0[2], b0[2], d); d = fmaf(a0[3], b0[3], d);
  d = fmaf(a1[0], b1[0], d); d = fmaf(a1[1], b1[1], d);
  d = fmaf(a1[2], b1[2], d); d = fmaf(a1[3], b1[3], d);
  return d;
}

// ---------------- zero only the borders of xpad/ypad ----------------
__global__ __launch_bounds__(256)
void zero_borders(unsigned short* __restrict__ xpad, unsigned short* __restrict__ ypad) {
  const int NPOS = 968;
  const int total = 2 * 2 * NPOS * 24;
  int idx = blockIdx.x * 256 + threadIdx.x;
  if (idx >= total) return;
  const int ch = idx % 24; int q = idx / 24;
  const int pos = q % NPOS; q /= NPOS;
  const int b = q & 1; const int buf = q >> 1;
  int row, col;
  if (pos < 328) { row = (pos < 164) ? 0 : 161; col = pos % 164; }
  else { int r = pos - 328; row = 1 + (r >> 2); int cm = r & 3; col = cm == 0 ? 0 : 160 + cm; }
  unsigned short* p = (buf ? ypad : xpad) + (((size_t)b * HPR + row) * HPW + col) * 192 + ch * 8;
  short8 z = {};
  *(short8*)p = z;
}

// ---------------- NCHW fp32 -> padded NHWC bf16 ----------------
__global__ __launch_bounds__(256)
void nchw2nhwc_pad(const float* __restrict__ x, unsigned short* __restrict__ xpad) {
  __shared__ float tile[192][33];
  int blk = blockIdx.x;
  const int w0 = (blk % 5) * 32; blk /= 5;
  const int h = blk % 160;
  const int b = blk / 160;
  const int t = threadIdx.x;
  for (int i = t; i < 192 * 32; i += 256) {
    int c = i >> 5, w = i & 31;
    tile[c][w] = x[(((size_t)b * 192 + c) * 160 + h) * 160 + w0 + w];
  }
  __syncthreads();
  for (int i = t; i < 32 * 192; i += 256) {
    int w = i / 192, c = i % 192;
    xpad[(((size_t)b * HPR + h + 1) * HPW + w0 + w + 1) * 192 + c] = f2bf(tile[c][w]);
  }
}

// ---------------- weights OIHW fp32 -> per-fragment layout ----------------
// dst frag id (tap, cs, cotile); within frag: lane-contiguous 16B:
// wtr[(((tap*6+cs)*NT + cotile)*64 + kh*16 + cor)*8 + j], ci = cs*32+kh*8+j, co = cotile*16+cor
__global__ __launch_bounds__(256)
void wtransformA(const float* __restrict__ w, unsigned short* __restrict__ wtr, int CO, int CI) {
  int id = blockIdx.x * 256 + threadIdx.x;  // co*CI + ci
  if (id >= CO * CI) return;
  const int co = id / CI, ci = id % CI;
  const int cs = ci >> 5, kh = (ci >> 3) & 3, j = ci & 7;
  const int cotile = co >> 4, cor = co & 15;
  const int NT = CO / 16;
  const float* wp = w + (size_t)id * 9;
#pragma unroll
  for (int tap = 0; tap < 9; ++tap)
    wtr[((((size_t)tap * 6 + cs) * NT + cotile) * 64 + kh * 16 + cor) * 8 + j] = f2bf(wp[tap]);
}

// ---------------- conv3x3 SAME, implicit GEMM, 2-phase double-buffered ----------------
// xin: padded NHWC bf16 [B][162][164][192]; wtrA: fragment layout (above).
// Block: 4 waves, one h-row each; wave tile 80w x 64co (acc 5x4). BH=4, slab R=6 rows.
// Per cs: loadA(36 frags) -> stage(next slab) -> 3 ky groups of 60 MFMA -> barrier.
template<int COUT, int OUTMODE>
__global__ __launch_bounds__(256, 2)
void conv_mfma(const unsigned short* __restrict__ xin, const unsigned short* __restrict__ wtrA,
               const float* __restrict__ bias, unsigned short* __restrict__ obf,
               float* __restrict__ of32) {
  constexpr int CIN = 192;
  constexpr int BH = 4, R = 6;
  constexpr int TOTAL = R * 84 * 4;          // 2016 16B chunks per slab
  constexpr int SLAB = R * 84 * 32;          // shorts per buffer
  constexpr int NT = COUT / 16;
  __shared__ unsigned short slab[2 * SLAB];
  const int t = threadIdx.x, lane = t & 63, wid = t >> 6;
  const int bx = blockIdx.x, cog = blockIdx.y, b = blockIdx.z;
  const int ws = bx & 1, hb = bx >> 1;
  const int w0 = ws * 80, h0 = hb * BH;
  const int hr = wid;
  const int l15 = lane & 15, l4 = lane >> 4;
  const int co0 = cog * 64;

  f32x4 acc[5][4];
#pragma unroll
  for (int ct = 0; ct < 4; ++ct) {
    f32x4 bi;
#pragma unroll
    for (int r = 0; r < 4; ++r) bi[r] = bias[co0 + ct * 16 + l4 * 4 + r];
#pragma unroll
    for (int mt = 0; mt < 5; ++mt) acc[mt][ct] = bi;
  }

  auto stage = [&](int cs, int bufbase) {
#pragma unroll
    for (int ib0 = 0; ib0 < 8; ++ib0) {
      const int ib = ib0 * 4 + wid;
      const int n = ib * 64 + lane;
      if (n < TOTAL) {
        const int c = n & 3, q = n >> 2;
        const int r = q / 84, wv = q - r * 84;
        const int csrc = c ^ ((wv >> 1) & 3);
        const unsigned short* g = xin +
            (((size_t)b * HPR + h0 + r) * HPW + w0 + wv) * CIN + cs * 32 + csrc * 8;
        gl16(g, &slab[bufbase + ib * 512]);
      }
    }
  };
  auto loadA = [&](short8* a, int cs, int ky) {
#pragma unroll
    for (int kx = 0; kx < 3; ++kx)
#pragma unroll
      for (int ct = 0; ct < 4; ++ct)
        a[kx * 4 + ct] = *(const short8*)(wtrA +
            ((size_t)((ky * 3 + kx) * 6 + cs) * NT + cog * 4 + ct) * 512 + lane * 8);
  };
  auto group = [&](const short8* a, int ky, int bufbase) {
    const unsigned short* srow = &slab[bufbase + (hr + ky) * 84 * 32];
#pragma unroll
    for (int kx = 0; kx < 3; ++kx)
#pragma unroll
      for (int mt = 0; mt < 5; ++mt) {
        const int wv = mt * 16 + l15 + kx;
        const int cr = l4 ^ ((wv >> 1) & 3);
        short8 bf = *(const short8*)(srow + wv * 32 + cr * 8);
#pragma unroll
        for (int ct = 0; ct < 4; ++ct)
          acc[mt][ct] = __builtin_amdgcn_mfma_f32_16x16x32_bf16(a[kx * 4 + ct], bf, acc[mt][ct], 0, 0, 0);
      }
  };

  stage(0, 0);
  __syncthreads();
  int cur = 0;
  for (int cs = 0; cs < 6; ++cs) {
    const int base = cur * SLAB, nbase = (cur ^ 1) * SLAB;
    short8 a0[12], a1[12], a2[12];
    loadA(a0, cs, 0);
    loadA(a1, cs, 1);
    loadA(a2, cs, 2);
    if (cs < 5) stage(cs + 1, nbase);   // issue next-slab loads; latency hides under MFMAs
    group(a0, 0, base);
    group(a1, 1, base);
    group(a2, 2, base);
    __syncthreads();                    // drains gl16 (done by now) + protects buffer swap
    cur ^= 1;
  }

  // ---- epilogue: D row = co (l4*4+r), col = w (l15) ----
  const int h = h0 + hr;
  if (OUTMODE == 0) {
#pragma unroll
    for (int mt = 0; mt < 5; ++mt) {
      const int w = w0 + mt * 16 + l15;
      unsigned short* dst0 = obf + (((size_t)b * Hc + h) * Wc + w) * 384 + co0 + l4 * 4;
#pragma unroll
      for (int ct = 0; ct < 4; ++ct) {
        short4v s;
#pragma unroll
        for (int r = 0; r < 4; ++r) s[r] = (short)f2bf(acc[mt][ct][r]);
        *(short4v*)(dst0 + ct * 16) = s;
      }
    }
  } else {
#pragma unroll
    for (int mt = 0; mt < 5; ++mt) {
      const int w = w0 + mt * 16 + l15;
#pragma unroll
      for (int ct = 0; ct < 4; ++ct)
#pragma unroll
        for (int r = 0; r < 4; ++r) {
          const int co = co0 + ct * 16 + l4 * 4 + r;
          of32[(((size_t)b * COUT + co) * Hc + h) * Wc + w] = acc[mt][ct][r];
        }
    }
  }
}

// ---------------- CPB relative-position bias: 81 entries x 8 heads ----------------
__global__ __launch_bounds__(64)
void cpb_bias_kernel(const float* __restrict__ w1, const float* __restrict__ b1,
                     const float* __restrict__ w2, float* __restrict__ biasf) {
  const int e = blockIdx.x;
  const int d0 = e / 9, d1 = e % 9;
  const int r0 = d0 - 4, r1 = d1 - 4;
  float t0 = log2f(fabsf((float)r0) * 2.0f + 1.0f) * (1.0f / 3.0f); if (r0 < 0) t0 = -t0;
  float t1 = log2f(fabsf((float)r1) * 2.0f + 1.0f) * (1.0f / 3.0f); if (r1 < 0) t1 = -t1;
  const int lane = threadIdx.x;
  float acc[8];
#pragma unroll
  for (int n = 0; n < 8; ++n) acc[n] = 0.f;
  for (int k = lane; k < 512; k += 64) {
    float hk = fmaf(t0, w1[k * 2 + 0], fmaf(t1, w1[k * 2 + 1], b1[k]));
    hk = fmaxf(hk, 0.f);
#pragma unroll
    for (int n = 0; n < 8; ++n) acc[n] = fmaf(hk, w2[n * 512 + k], acc[n]);
  }
#pragma unroll
  for (int n = 0; n < 8; ++n) {
#pragma unroll
    for (int off = 32; off > 0; off >>= 1) acc[n] += __shfl_xor(acc[n], off, 64);
  }
  if (lane == 0) {
#pragma unroll
    for (int n = 0; n < 8; ++n)
      biasf[e * 8 + n] = 16.0f / (1.0f + expf(-acc[n]));
  }
}

// ---------------- 5x5 window cosine attention (both variants fused) ----------------
__global__ __launch_bounds__(256)
void win_attn_kernel(const unsigned short* __restrict__ xq, const float* __restrict__ biasf,
                     const float* __restrict__ logit_scale, unsigned short* __restrict__ ypad) {
  __shared__ f32x4 kn4[8][25][2];
  __shared__ f32x4 vv4[8][25][2];
  const int head = threadIdx.x >> 5;
  const int i = threadIdx.x & 31;
  const int variant = blockIdx.y;
  const int chan_off = variant ? 128 : 0;
  const int y_ch_off = variant ? 64 : 0;
  const int shift_in = variant ? 3 : 0;
  const int shift_out = variant ? 2 : 0;
  int blk = blockIdx.x;
  const int wb_i = blk % 32; blk /= 32;
  const int hb_i = blk;
  const int b = blockIdx.z;
  const int wi = i / 5, wj = i % 5;
  const int gh = hb_i * 5 + wi, gw = wb_i * 5 + wj;
  const int sh = (gh + shift_in) % Hc, sw = (gw + shift_in) % Wc;

  if (i < 25) {
    const unsigned short* base = xq + (((size_t)b * Hc + sh) * Wc + sw) * 384 + chan_off + head * 8;
    short8 kv = *(const short8*)base;
    short8 vv = *(const short8*)(base + 64);
    float k[8]; float nrm = 0.f;
#pragma unroll
    for (int c = 0; c < 8; ++c) { k[c] = bf2f((unsigned short)kv[c]); nrm = fmaf(k[c], k[c], nrm); }
    const float inv = 1.0f / fmaxf(sqrtf(nrm), 1e-12f);
    f32x4 a0, a1, b0, b1;
#pragma unroll
    for (int c = 0; c < 4; ++c) { a0[c] = k[c] * inv; a1[c] = k[c + 4] * inv; }
#pragma unroll
    for (int c = 0; c < 4; ++c) { b0[c] = bf2f((unsigned short)vv[c]); b1[c] = bf2f((unsigned short)vv[c + 4]); }
    kn4[head][i][0] = a0; kn4[head][i][1] = a1;
    vv4[head][i][0] = b0; vv4[head][i][1] = b1;
  }
  __syncthreads();
  if (i >= 25) return;

  const float scale = expf(fminf(logit_scale[head], 4.6051702f));
  const f32x4 q0 = kn4[head][i][0], q1 = kn4[head][i][1];
  float s[25];
#pragma unroll
  for (int j = 0; j < 25; ++j) {
    const float d = dot8(q0, q1, kn4[head][j][0], kn4[head][j][1]);
    const int d0 = wi - (j / 5) + 4, d1 = wj - (j % 5) + 4;
    s[j] = fmaf(d, scale, biasf[(d0 * 9 + d1) * 8 + head]);
  }
  float m = -1e30f;
#pragma unroll
  for (int j = 0; j < 25; ++j) m = fmaxf(m, s[j]);
  float den = 0.f;
  f32x4 acc0 = {0.f, 0.f, 0.f, 0.f}, acc1 = {0.f, 0.f, 0.f, 0.f};
#pragma unroll
  for (int j = 0; j < 25; ++j) {
    const float p = __expf(s[j] - m);
    den += p;
    acc0 += vv4[head][j][0] * p;
    acc1 += vv4[head][j][1] * p;
  }
  const float rden = 1.0f / den;
  const int oh = (gh + shift_out) % Hc, ow = (gw + shift_out) % Wc;
  short8 o;
#pragma unroll
  for (int c = 0; c < 4; ++c) { o[c] = (short)f2bf(acc0[c] * rden); o[c + 4] = (short)f2bf(acc1[c] * rden); }
  *(short8*)(ypad + (((size_t)b * HPR + oh + 1) * HPW + ow + 1) * 192 + y_ch_off + head * 8) = o;
}

// ---------------- axial row pass -> vrow bf16 [b][head][h][w][8] ----------------
__global__ __launch_bounds__(192)
void row_attn_kernel(const unsigned short* __restrict__ xq, const float* __restrict__ lrs,
                     unsigned short* __restrict__ vrow) {
  __shared__ f32x4 kn4[160][2];
  __shared__ f32x4 vv4[160][2];
  int blk = blockIdx.x;
  const int head = blk % 8; blk /= 8;
  const int h = blk % 160; blk /= 160;
  const int b = blk;
  const int i = threadIdx.x;

  if (i < 160) {
    const unsigned short* base = xq + (((size_t)b * Hc + h) * Wc + i) * 384 + 256 + head * 8;
    short8 kv = *(const short8*)base;
    short8 vv = *(const short8*)(base + 64);
    float k[8]; float nrm = 0.f;
#pragma unroll
    for (int c = 0; c < 8; ++c) { k[c] = bf2f((unsigned short)kv[c]); nrm = fmaf(k[c], k[c], nrm); }
    const float inv = 1.0f / fmaxf(sqrtf(nrm), 1e-12f);
    f32x4 a0, a1, b0, b1;
#pragma unroll
    for (int c = 0; c < 4; ++c) { a0[c] = k[c] * inv; a1[c] = k[c + 4] * inv; }
#pragma unroll
    for (int c = 0; c < 4; ++c) { b0[c] = bf2f((unsigned short)vv[c]); b1[c] = bf2f((unsigned short)vv[c + 4]); }
    kn4[i][0] = a0; kn4[i][1] = a1;
    vv4[i][0] = b0; vv4[i][1] = b1;
  }
  __syncthreads();
  if (i >= 160) return;

  const float scale = expf(fminf(lrs[head], 4.6051702f));
  const f32x4 q0 = kn4[i][0], q1 = kn4[i][1];
  float den = 0.f;
  f32x4 acc0 = {0.f, 0.f, 0.f, 0.f}, acc1 = {0.f, 0.f, 0.f, 0.f};
  for (int j = 0; j < 160; ++j) {
    const float d = dot8(q0, q1, kn4[j][0], kn4[j][1]);
    const float p = __expf(fmaf(d, scale, -scale));
    den += p;
    acc0 += vv4[j][0] * p;
    acc1 += vv4[j][1] * p;
  }
  const float rden = 1.0f / den;
  short8 o;
#pragma unroll
  for (int c = 0; c < 4; ++c) { o[c] = (short)f2bf(acc0[c] * rden); o[c + 4] = (short)f2bf(acc1[c] * rden); }
  *(short8*)(vrow + ((((size_t)b * 8 + head) * 160 + h) * 160 + i) * 8) = o;
}

// ---------------- axial column pass -> ypad channels 128..191 ----------------
__global__ __launch_bounds__(192)
void col_attn_kernel(const unsigned short* __restrict__ xq, const float* __restrict__ lrs,
                     const unsigned short* __restrict__ vrow, unsigned short* __restrict__ ypad) {
  __shared__ f32x4 kn4[160][2];
  __shared__ f32x4 vv4[160][2];
  int blk = blockIdx.x;
  const int head = blk % 8; blk /= 8;
  const int w = blk % 160; blk /= 160;
  const int b = blk;
  const int i = threadIdx.x;

  if (i < 160) {
    const unsigned short* kb = xq + (((size_t)b * Hc + i) * Wc + w) * 384 + 256 + head * 8;
    short8 kv = *(const short8*)kb;
    short8 vv = *(const short8*)(vrow + ((((size_t)b * 8 + head) * 160 + i) * 160 + w) * 8);
    float k[8]; float nrm = 0.f;
#pragma unroll
    for (int c = 0; c < 8; ++c) { k[c] = bf2f((unsigned short)kv[c]); nrm = fmaf(k[c], k[c], nrm); }
    const float inv = 1.0f / fmaxf(sqrtf(nrm), 1e-12f);
    f32x4 a0, a1, b0, b1;
#pragma unroll
    for (int c = 0; c < 4; ++c) { a0[c] = k[c] * inv; a1[c] = k[c + 4] * inv; }
#pragma unroll
    for (int c = 0; c < 4; ++c) { b0[c] = bf2f((unsigned short)vv[c]); b1[c] = bf2f((unsigned short)vv[c + 4]); }
    kn4[i][0] = a0; kn4[i][1] = a1;
    vv4[i][0] = b0; vv4[i][1] = b1;
  }
  __syncthreads();
  if (i >= 160) return;

  const float scale = expf(fminf(lrs[head], 4.6051702f));
  const f32x4 q0 = kn4[i][0], q1 = kn4[i][1];
  float den = 0.f;
  f32x4 acc0 = {0.f, 0.f, 0.f, 0.f}, acc1 = {0.f, 0.f, 0.f, 0.f};
  for (int j = 0; j < 160; ++j) {
    const float d = dot8(q0, q1, kn4[j][0], kn4[j][1]);
    const float p = __expf(fmaf(d, scale, -scale));
    den += p;
    acc0 += vv4[j][0] * p;
    acc1 += vv4[j][1] * p;
  }
  const float rden = 1.0f / den;
  short8 o;
#pragma unroll
  for (int c = 0; c < 4; ++c) { o[c] = (short)f2bf(acc0[c] * rden); o[c + 4] = (short)f2bf(acc1[c] * rden); }
  *(short8*)(ypad + (((size_t)b * HPR + i + 1) * HPW + w + 1) * 192 + 128 + head * 8) = o;
}

extern "C" void kernel_launch(void* const* d_in, const int* in_sizes, int n_in,
                              void* d_out, int out_size, void* d_ws, size_t ws_size,
                              hipStream_t stream) {
  const float* x     = (const float*)d_in[0];
  const float* w_in  = (const float*)d_in[1];
  const float* b_in  = (const float*)d_in[2];
  const float* w_out = (const float*)d_in[3];
  const float* b_out = (const float*)d_in[4];
  const float* ls    = (const float*)d_in[5];
  const float* lrs   = (const float*)d_in[6];
  const float* cw1   = (const float*)d_in[7];
  const float* cb1   = (const float*)d_in[8];
  const float* cw2   = (const float*)d_in[9];
  float* out = (float*)d_out;

  // workspace layout
  char* p = (char*)d_ws;
  unsigned short* xpad = (unsigned short*)p;  p += (size_t)Bc * HPR * HPW * 192 * 2;   // 20.4 MB
  unsigned short* ypad = (unsigned short*)p;  p += (size_t)Bc * HPR * HPW * 192 * 2;   // 20.4 MB
  unsigned short* xq   = (unsigned short*)p;  p += (size_t)Bc * Hc * Wc * 384 * 2;     // 39.3 MB
  unsigned short* vrow = (unsigned short*)p;  p += (size_t)Bc * 8 * Hc * Wc * 8 * 2;   //  6.6 MB
  unsigned short* wtr1 = (unsigned short*)p;  p += (size_t)9 * 384 * 192 * 2;          //  1.3 MB
  unsigned short* wtr2 = (unsigned short*)p;  p += (size_t)9 * 192 * 192 * 2;          //  0.7 MB
  float* biasf = (float*)p;

  zero_borders<<<(2 * 2 * 968 * 24 + 255) / 256, 256, 0, stream>>>(xpad, ypad);
  nchw2nhwc_pad<<<Bc * 160 * 5, 256, 0, stream>>>(x, xpad);
  wtransformA<<<(384 * 192 + 255) / 256, 256, 0, stream>>>(w_in, wtr1, 384, 192);
  wtransformA<<<(192 * 192 + 255) / 256, 256, 0, stream>>>(w_out, wtr2, 192, 192);
  cpb_bias_kernel<<<81, 64, 0, stream>>>(cw1, cb1, cw2, biasf);
  // conv_in 192->384: grid (2ws x 40hb, 6 cog, 2 b)
  conv_mfma<384, 0><<<dim3(80, 6, Bc), 256, 0, stream>>>(xpad, wtr1, b_in, xq, nullptr);
  // attention branches (write ypad interior)
  win_attn_kernel<<<dim3(1024, 2, Bc), 256, 0, stream>>>(xq, biasf, ls, ypad);
  row_attn_kernel<<<Bc * 160 * 8, 192, 0, stream>>>(xq, lrs, vrow);
  col_attn_kernel<<<Bc * 160 * 8, 192, 0, stream>>>(xq, lrs, vrow, ypad);
  // conv_out 192->192: grid (80, 3, 2)
  conv_mfma<192, 1><<<dim3(80, 3, Bc), 256, 0, stream>>>(ypad, wtr2, b_out, nullptr, out);
}

// Round 6
// 267.778 us; speedup vs baseline: 8.4604x; 1.1800x over previous
//
#include <hip/hip_runtime.h>
#include <math.h>

// GeoAB: conv3x3(192->384, bf16 MFMA, 2-phase + A-reg ping-pong) -> [win attn fused | axial attn]
//        -> conv3x3(192->192, bf16 MFMA).  B=2, H=W=160, WS=5, NH=8, CPH=8.

typedef __attribute__((ext_vector_type(8))) short short8;
typedef __attribute__((ext_vector_type(4))) short short4v;
typedef __attribute__((ext_vector_type(4))) float f32x4;

constexpr int Hc = 160, Wc = 160, Bc = 2;
constexpr int HPR = 162;   // padded rows
constexpr int HPW = 164;   // padded cols

__device__ inline unsigned short f2bf(float f) {
  union { float f; unsigned u; } v; v.f = f;
  unsigned r = v.u + 0x7FFF + ((v.u >> 16) & 1);
  return (unsigned short)(r >> 16);
}
__device__ inline float bf2f(unsigned short h) {
  union { unsigned u; float f; } v; v.u = ((unsigned)h) << 16;
  return v.f;
}

__device__ inline void gl16(const void* g, void* l) {
  __builtin_amdgcn_global_load_lds((const __attribute__((address_space(1))) unsigned int*)g,
                                   (__attribute__((address_space(3))) unsigned int*)l, 16, 0, 0);
}

__device__ inline float dot8(f32x4 a0, f32x4 a1, f32x4 b0, f32x4 b1) {
  float d = a0[0] * b0[0];
  d = fmaf(a0[1], b0[1], d); d = fmaf(a0[2], b0[2], d); d = fmaf(a0[3], b0[3], d);
  d = fmaf(a1[0], b1[0], d); d = fmaf(a1[1], b1[1], d);
  d = fmaf(a1[2], b1[2], d); d = fmaf(a1[3], b1[3], d);
  return d;
}

// ---------------- zero only the borders of xpad/ypad ----------------
__global__ __launch_bounds__(256)
void zero_borders(unsigned short* __restrict__ xpad, unsigned short* __restrict__ ypad) {
  const int NPOS = 968;
  const int total = 2 * 2 * NPOS * 24;
  int idx = blockIdx.x * 256 + threadIdx.x;
  if (idx >= total) return;
  const int ch = idx % 24; int q = idx / 24;
  const int pos = q % NPOS; q /= NPOS;
  const int b = q & 1; const int buf = q >> 1;
  int row, col;
  if (pos < 328) { row = (pos < 164) ? 0 : 161; col = pos % 164; }
  else { int r = pos - 328; row = 1 + (r >> 2); int cm = r & 3; col = cm == 0 ? 0 : 160 + cm; }
  unsigned short* p = (buf ? ypad : xpad) + (((size_t)b * HPR + row) * HPW + col) * 192 + ch * 8;
  short8 z = {};
  *(short8*)p = z;
}

// ---------------- NCHW fp32 -> padded NHWC bf16 ----------------
__global__ __launch_bounds__(256)
void nchw2nhwc_pad(const float* __restrict__ x, unsigned short* __restrict__ xpad) {
  __shared__ float tile[192][33];
  int blk = blockIdx.x;
  const int w0 = (blk % 5) * 32; blk /= 5;
  const int h = blk % 160;
  const int b = blk / 160;
  const int t = threadIdx.x;
  for (int i = t; i < 192 * 32; i += 256) {
    int c = i >> 5, w = i & 31;
    tile[c][w] = x[(((size_t)b * 192 + c) * 160 + h) * 160 + w0 + w];
  }
  __syncthreads();
  for (int i = t; i < 32 * 192; i += 256) {
    int w = i / 192, c = i % 192;
    xpad[(((size_t)b * HPR + h + 1) * HPW + w0 + w + 1) * 192 + c] = f2bf(tile[c][w]);
  }
}

// ---------------- weights OIHW fp32 -> per-fragment layout ----------------
// frag id (tap, cs, cotile); within frag lane-contiguous 16B:
// wtr[(((tap*6+cs)*NT + cotile)*64 + kh*16 + cor)*8 + j], ci = cs*32+kh*8+j, co = cotile*16+cor
__global__ __launch_bounds__(256)
void wtransformA(const float* __restrict__ w, unsigned short* __restrict__ wtr, int CO, int CI) {
  int id = blockIdx.x * 256 + threadIdx.x;  // co*CI + ci
  if (id >= CO * CI) return;
  const int co = id / CI, ci = id % CI;
  const int cs = ci >> 5, kh = (ci >> 3) & 3, j = ci & 7;
  const int cotile = co >> 4, cor = co & 15;
  const int NT = CO / 16;
  const float* wp = w + (size_t)id * 9;
#pragma unroll
  for (int tap = 0; tap < 9; ++tap)
    wtr[((((size_t)tap * 6 + cs) * NT + cotile) * 64 + kh * 16 + cor) * 8 + j] = f2bf(wp[tap]);
}

// ---------------- conv3x3 SAME, implicit GEMM, 2-phase + A ping-pong ----------------
// Block: 4 waves, one h-row each; wave tile 80w x 64co (acc 5x4). BH=4, slab R=6 rows.
// Per cs: stage(next B slab); then per ky: prefetch A(ky+1) in regs, compute group(ky).
// A working set per (cs,ky) = 12KB -> L1-resident across the CU's 8 waves.
template<int COUT, int OUTMODE>
__global__ __launch_bounds__(256, 2)
void conv_mfma(const unsigned short* __restrict__ xin, const unsigned short* __restrict__ wtrA,
               const float* __restrict__ bias, unsigned short* __restrict__ obf,
               float* __restrict__ of32) {
  constexpr int CIN = 192;
  constexpr int BH = 4, R = 6;
  constexpr int TOTAL = R * 84 * 4;          // 2016 16B chunks per slab
  constexpr int SLAB = R * 84 * 32;          // shorts per buffer
  constexpr int NT = COUT / 16;
  __shared__ unsigned short slab[2 * SLAB];
  const int t = threadIdx.x, lane = t & 63, wid = t >> 6;
  const int bx = blockIdx.x, cog = blockIdx.y, b = blockIdx.z;
  const int ws = bx & 1, hb = bx >> 1;
  const int w0 = ws * 80, h0 = hb * BH;
  const int hr = wid;
  const int l15 = lane & 15, l4 = lane >> 4;
  const int co0 = cog * 64;

  f32x4 acc[5][4];
#pragma unroll
  for (int ct = 0; ct < 4; ++ct) {
    f32x4 bi;
#pragma unroll
    for (int r = 0; r < 4; ++r) bi[r] = bias[co0 + ct * 16 + l4 * 4 + r];
#pragma unroll
    for (int mt = 0; mt < 5; ++mt) acc[mt][ct] = bi;
  }

  auto stage = [&](int cs, int bufbase) {
#pragma unroll
    for (int ib0 = 0; ib0 < 8; ++ib0) {
      const int ib = ib0 * 4 + wid;
      const int n = ib * 64 + lane;
      if (n < TOTAL) {
        const int c = n & 3, q = n >> 2;
        const int r = q / 84, wv = q - r * 84;
        const int csrc = c ^ ((wv >> 1) & 3);
        const unsigned short* g = xin +
            (((size_t)b * HPR + h0 + r) * HPW + w0 + wv) * CIN + cs * 32 + csrc * 8;
        gl16(g, &slab[bufbase + ib * 512]);
      }
    }
  };

// load 12 A-frags (one ky group) into register array a
#define LOADA(a, ky, cs)                                                         \
  {                                                                              \
    _Pragma("unroll")                                                            \
    for (int kx = 0; kx < 3; ++kx) {                                             \
      _Pragma("unroll")                                                          \
      for (int ct = 0; ct < 4; ++ct)                                             \
        a[kx * 4 + ct] = *(const short8*)(wtrA +                                 \
            ((size_t)(((ky) * 3 + kx) * 6 + (cs)) * NT + cog * 4 + ct) * 512 +   \
            lane * 8);                                                           \
    }                                                                            \
  }

// 60 MFMAs of one ky group against slab buffer at bufbase
#define GROUP(a, ky, bufbase)                                                    \
  {                                                                              \
    const unsigned short* srow = &slab[(bufbase) + (hr + (ky)) * 84 * 32];       \
    _Pragma("unroll")                                                            \
    for (int kx = 0; kx < 3; ++kx) {                                             \
      _Pragma("unroll")                                                          \
      for (int mt = 0; mt < 5; ++mt) {                                           \
        const int wv = mt * 16 + l15 + kx;                                       \
        const int cr = l4 ^ ((wv >> 1) & 3);                                     \
        short8 bf = *(const short8*)(srow + wv * 32 + cr * 8);                   \
        _Pragma("unroll")                                                        \
        for (int ct = 0; ct < 4; ++ct)                                           \
          acc[mt][ct] =                                                          \
              __builtin_amdgcn_mfma_f32_16x16x32_bf16(a[kx * 4 + ct], bf,        \
                                                      acc[mt][ct], 0, 0, 0);     \
      }                                                                          \
    }                                                                            \
  }

// one cs step: P holds (cs, ky0) on entry; on exit Q holds (cs+1, ky0)
#define CSBODY(P, Q, cs, base, nbase)                                            \
  {                                                                              \
    if ((cs) < 5) stage((cs) + 1, nbase);                                        \
    LOADA(Q, 1, cs);                                                             \
    GROUP(P, 0, base);                                                           \
    LOADA(P, 2, cs);                                                             \
    GROUP(Q, 1, base);                                                           \
    if ((cs) < 5) LOADA(Q, 0, (cs) + 1);                                         \
    GROUP(P, 2, base);                                                           \
    __syncthreads();                                                             \
  }

  short8 Pf[12], Qf[12];
  stage(0, 0);
  LOADA(Pf, 0, 0);
  __syncthreads();

  CSBODY(Pf, Qf, 0, 0, SLAB);
  CSBODY(Qf, Pf, 1, SLAB, 0);
  CSBODY(Pf, Qf, 2, 0, SLAB);
  CSBODY(Qf, Pf, 3, SLAB, 0);
  CSBODY(Pf, Qf, 4, 0, SLAB);
  CSBODY(Qf, Pf, 5, SLAB, 0);
#undef LOADA
#undef GROUP
#undef CSBODY

  // ---- epilogue: D row = co (l4*4+r), col = w (l15) ----
  const int h = h0 + hr;
  if (OUTMODE == 0) {
#pragma unroll
    for (int mt = 0; mt < 5; ++mt) {
      const int w = w0 + mt * 16 + l15;
      unsigned short* dst0 = obf + (((size_t)b * Hc + h) * Wc + w) * 384 + co0 + l4 * 4;
#pragma unroll
      for (int ct = 0; ct < 4; ++ct) {
        short4v s;
#pragma unroll
        for (int r = 0; r < 4; ++r) s[r] = (short)f2bf(acc[mt][ct][r]);
        *(short4v*)(dst0 + ct * 16) = s;
      }
    }
  } else {
#pragma unroll
    for (int mt = 0; mt < 5; ++mt) {
      const int w = w0 + mt * 16 + l15;
#pragma unroll
      for (int ct = 0; ct < 4; ++ct)
#pragma unroll
        for (int r = 0; r < 4; ++r) {
          const int co = co0 + ct * 16 + l4 * 4 + r;
          of32[(((size_t)b * COUT + co) * Hc + h) * Wc + w] = acc[mt][ct][r];
        }
    }
  }
}

// ---------------- CPB relative-position bias: 81 entries x 8 heads ----------------
__global__ __launch_bounds__(64)
void cpb_bias_kernel(const float* __restrict__ w1, const float* __restrict__ b1,
                     const float* __restrict__ w2, float* __restrict__ biasf) {
  const int e = blockIdx.x;
  const int d0 = e / 9, d1 = e % 9;
  const int r0 = d0 - 4, r1 = d1 - 4;
  float t0 = log2f(fabsf((float)r0) * 2.0f + 1.0f) * (1.0f / 3.0f); if (r0 < 0) t0 = -t0;
  float t1 = log2f(fabsf((float)r1) * 2.0f + 1.0f) * (1.0f / 3.0f); if (r1 < 0) t1 = -t1;
  const int lane = threadIdx.x;
  float acc[8];
#pragma unroll
  for (int n = 0; n < 8; ++n) acc[n] = 0.f;
  for (int k = lane; k < 512; k += 64) {
    float hk = fmaf(t0, w1[k * 2 + 0], fmaf(t1, w1[k * 2 + 1], b1[k]));
    hk = fmaxf(hk, 0.f);
#pragma unroll
    for (int n = 0; n < 8; ++n) acc[n] = fmaf(hk, w2[n * 512 + k], acc[n]);
  }
#pragma unroll
  for (int n = 0; n < 8; ++n) {
#pragma unroll
    for (int off = 32; off > 0; off >>= 1) acc[n] += __shfl_xor(acc[n], off, 64);
  }
  if (lane == 0) {
#pragma unroll
    for (int n = 0; n < 8; ++n)
      biasf[e * 8 + n] = 16.0f / (1.0f + expf(-acc[n]));
  }
}

// ---------------- 5x5 window cosine attention (both variants fused) ----------------
__global__ __launch_bounds__(256)
void win_attn_kernel(const unsigned short* __restrict__ xq, const float* __restrict__ biasf,
                     const float* __restrict__ logit_scale, unsigned short* __restrict__ ypad) {
  __shared__ f32x4 kn4[8][25][2];
  __shared__ f32x4 vv4[8][25][2];
  const int head = threadIdx.x >> 5;
  const int i = threadIdx.x & 31;
  const int variant = blockIdx.y;
  const int chan_off = variant ? 128 : 0;
  const int y_ch_off = variant ? 64 : 0;
  const int shift_in = variant ? 3 : 0;
  const int shift_out = variant ? 2 : 0;
  int blk = blockIdx.x;
  const int wb_i = blk % 32; blk /= 32;
  const int hb_i = blk;
  const int b = blockIdx.z;
  const int wi = i / 5, wj = i % 5;
  const int gh = hb_i * 5 + wi, gw = wb_i * 5 + wj;
  const int sh = (gh + shift_in) % Hc, sw = (gw + shift_in) % Wc;

  if (i < 25) {
    const unsigned short* base = xq + (((size_t)b * Hc + sh) * Wc + sw) * 384 + chan_off + head * 8;
    short8 kv = *(const short8*)base;
    short8 vv = *(const short8*)(base + 64);
    float k[8]; float nrm = 0.f;
#pragma unroll
    for (int c = 0; c < 8; ++c) { k[c] = bf2f((unsigned short)kv[c]); nrm = fmaf(k[c], k[c], nrm); }
    const float inv = 1.0f / fmaxf(sqrtf(nrm), 1e-12f);
    f32x4 a0, a1, b0, b1;
#pragma unroll
    for (int c = 0; c < 4; ++c) { a0[c] = k[c] * inv; a1[c] = k[c + 4] * inv; }
#pragma unroll
    for (int c = 0; c < 4; ++c) { b0[c] = bf2f((unsigned short)vv[c]); b1[c] = bf2f((unsigned short)vv[c + 4]); }
    kn4[head][i][0] = a0; kn4[head][i][1] = a1;
    vv4[head][i][0] = b0; vv4[head][i][1] = b1;
  }
  __syncthreads();
  if (i >= 25) return;

  const float scale = expf(fminf(logit_scale[head], 4.6051702f));
  const f32x4 q0 = kn4[head][i][0], q1 = kn4[head][i][1];
  float s[25];
#pragma unroll
  for (int j = 0; j < 25; ++j) {
    const float d = dot8(q0, q1, kn4[head][j][0], kn4[head][j][1]);
    const int d0 = wi - (j / 5) + 4, d1 = wj - (j % 5) + 4;
    s[j] = fmaf(d, scale, biasf[(d0 * 9 + d1) * 8 + head]);
  }
  float m = -1e30f;
#pragma unroll
  for (int j = 0; j < 25; ++j) m = fmaxf(m, s[j]);
  float den = 0.f;
  f32x4 acc0 = {0.f, 0.f, 0.f, 0.f}, acc1 = {0.f, 0.f, 0.f, 0.f};
#pragma unroll
  for (int j = 0; j < 25; ++j) {
    const float p = __expf(s[j] - m);
    den += p;
    acc0 += vv4[head][j][0] * p;
    acc1 += vv4[head][j][1] * p;
  }
  const float rden = 1.0f / den;
  const int oh = (gh + shift_out) % Hc, ow = (gw + shift_out) % Wc;
  short8 o;
#pragma unroll
  for (int c = 0; c < 4; ++c) { o[c] = (short)f2bf(acc0[c] * rden); o[c + 4] = (short)f2bf(acc1[c] * rden); }
  *(short8*)(ypad + (((size_t)b * HPR + oh + 1) * HPW + ow + 1) * 192 + y_ch_off + head * 8) = o;
}

// ---------------- axial row pass -> vrow bf16 [b][head][h][w][8] ----------------
__global__ __launch_bounds__(192)
void row_attn_kernel(const unsigned short* __restrict__ xq, const float* __restrict__ lrs,
                     unsigned short* __restrict__ vrow) {
  __shared__ f32x4 kn4[160][2];
  __shared__ f32x4 vv4[160][2];
  int blk = blockIdx.x;
  const int head = blk % 8; blk /= 8;
  const int h = blk % 160; blk /= 160;
  const int b = blk;
  const int i = threadIdx.x;

  if (i < 160) {
    const unsigned short* base = xq + (((size_t)b * Hc + h) * Wc + i) * 384 + 256 + head * 8;
    short8 kv = *(const short8*)base;
    short8 vv = *(const short8*)(base + 64);
    float k[8]; float nrm = 0.f;
#pragma unroll
    for (int c = 0; c < 8; ++c) { k[c] = bf2f((unsigned short)kv[c]); nrm = fmaf(k[c], k[c], nrm); }
    const float inv = 1.0f / fmaxf(sqrtf(nrm), 1e-12f);
    f32x4 a0, a1, b0, b1;
#pragma unroll
    for (int c = 0; c < 4; ++c) { a0[c] = k[c] * inv; a1[c] = k[c + 4] * inv; }
#pragma unroll
    for (int c = 0; c < 4; ++c) { b0[c] = bf2f((unsigned short)vv[c]); b1[c] = bf2f((unsigned short)vv[c + 4]); }
    kn4[i][0] = a0; kn4[i][1] = a1;
    vv4[i][0] = b0; vv4[i][1] = b1;
  }
  __syncthreads();
  if (i >= 160) return;

  const float scale = expf(fminf(lrs[head], 4.6051702f));
  const f32x4 q0 = kn4[i][0], q1 = kn4[i][1];
  float den = 0.f;
  f32x4 acc0 = {0.f, 0.f, 0.f, 0.f}, acc1 = {0.f, 0.f, 0.f, 0.f};
  for (int j = 0; j < 160; ++j) {
    const float d = dot8(q0, q1, kn4[j][0], kn4[j][1]);
    const float p = __expf(fmaf(d, scale, -scale));
    den += p;
    acc0 += vv4[j][0] * p;
    acc1 += vv4[j][1] * p;
  }
  const float rden = 1.0f / den;
  short8 o;
#pragma unroll
  for (int c = 0; c < 4; ++c) { o[c] = (short)f2bf(acc0[c] * rden); o[c + 4] = (short)f2bf(acc1[c] * rden); }
  *(short8*)(vrow + ((((size_t)b * 8 + head) * 160 + h) * 160 + i) * 8) = o;
}

// ---------------- axial column pass -> ypad channels 128..191 ----------------
__global__ __launch_bounds__(192)
void col_attn_kernel(const unsigned short* __restrict__ xq, const float* __restrict__ lrs,
                     const unsigned short* __restrict__ vrow, unsigned short* __restrict__ ypad) {
  __shared__ f32x4 kn4[160][2];
  __shared__ f32x4 vv4[160][2];
  int blk = blockIdx.x;
  const int head = blk % 8; blk /= 8;
  const int w = blk % 160; blk /= 160;
  const int b = blk;
  const int i = threadIdx.x;

  if (i < 160) {
    const unsigned short* kb = xq + (((size_t)b * Hc + i) * Wc + w) * 384 + 256 + head * 8;
    short8 kv = *(const short8*)kb;
    short8 vv = *(const short8*)(vrow + ((((size_t)b * 8 + head) * 160 + i) * 160 + w) * 8);
    float k[8]; float nrm = 0.f;
#pragma unroll
    for (int c = 0; c < 8; ++c) { k[c] = bf2f((unsigned short)kv[c]); nrm = fmaf(k[c], k[c], nrm); }
    const float inv = 1.0f / fmaxf(sqrtf(nrm), 1e-12f);
    f32x4 a0, a1, b0, b1;
#pragma unroll
    for (int c = 0; c < 4; ++c) { a0[c] = k[c] * inv; a1[c] = k[c + 4] * inv; }
#pragma unroll
    for (int c = 0; c < 4; ++c) { b0[c] = bf2f((unsigned short)vv[c]); b1[c] = bf2f((unsigned short)vv[c + 4]); }
    kn4[i][0] = a0; kn4[i][1] = a1;
    vv4[i][0] = b0; vv4[i][1] = b1;
  }
  __syncthreads();
  if (i >= 160) return;

  const float scale = expf(fminf(lrs[head], 4.6051702f));
  const f32x4 q0 = kn4[i][0], q1 = kn4[i][1];
  float den = 0.f;
  f32x4 acc0 = {0.f, 0.f, 0.f, 0.f}, acc1 = {0.f, 0.f, 0.f, 0.f};
  for (int j = 0; j < 160; ++j) {
    const float d = dot8(q0, q1, kn4[j][0], kn4[j][1]);
    const float p = __expf(fmaf(d, scale, -scale));
    den += p;
    acc0 += vv4[j][0] * p;
    acc1 += vv4[j][1] * p;
  }
  const float rden = 1.0f / den;
  short8 o;
#pragma unroll
  for (int c = 0; c < 4; ++c) { o[c] = (short)f2bf(acc0[c] * rden); o[c + 4] = (short)f2bf(acc1[c] * rden); }
  *(short8*)(ypad + (((size_t)b * HPR + i + 1) * HPW + w + 1) * 192 + 128 + head * 8) = o;
}

extern "C" void kernel_launch(void* const* d_in, const int* in_sizes, int n_in,
                              void* d_out, int out_size, void* d_ws, size_t ws_size,
                              hipStream_t stream) {
  const float* x     = (const float*)d_in[0];
  const float* w_in  = (const float*)d_in[1];
  const float* b_in  = (const float*)d_in[2];
  const float* w_out = (const float*)d_in[3];
  const float* b_out = (const float*)d_in[4];
  const float* ls    = (const float*)d_in[5];
  const float* lrs   = (const float*)d_in[6];
  const float* cw1   = (const float*)d_in[7];
  const float* cb1   = (const float*)d_in[8];
  const float* cw2   = (const float*)d_in[9];
  float* out = (float*)d_out;

  // workspace layout
  char* p = (char*)d_ws;
  unsigned short* xpad = (unsigned short*)p;  p += (size_t)Bc * HPR * HPW * 192 * 2;   // 20.4 MB
  unsigned short* ypad = (unsigned short*)p;  p += (size_t)Bc * HPR * HPW * 192 * 2;   // 20.4 MB
  unsigned short* xq   = (unsigned short*)p;  p += (size_t)Bc * Hc * Wc * 384 * 2;     // 39.3 MB
  unsigned short* vrow = (unsigned short*)p;  p += (size_t)Bc * 8 * Hc * Wc * 8 * 2;   //  6.6 MB
  unsigned short* wtr1 = (unsigned short*)p;  p += (size_t)9 * 384 * 192 * 2;          //  1.3 MB
  unsigned short* wtr2 = (unsigned short*)p;  p += (size_t)9 * 192 * 192 * 2;          //  0.7 MB
  float* biasf = (float*)p;

  zero_borders<<<(2 * 2 * 968 * 24 + 255) / 256, 256, 0, stream>>>(xpad, ypad);
  nchw2nhwc_pad<<<Bc * 160 * 5, 256, 0, stream>>>(x, xpad);
  wtransformA<<<(384 * 192 + 255) / 256, 256, 0, stream>>>(w_in, wtr1, 384, 192);
  wtransformA<<<(192 * 192 + 255) / 256, 256, 0, stream>>>(w_out, wtr2, 192, 192);
  cpb_bias_kernel<<<81, 64, 0, stream>>>(cw1, cb1, cw2, biasf);
  // conv_in 192->384: grid (2ws x 40hb, 6 cog, 2 b)
  conv_mfma<384, 0><<<dim3(80, 6, Bc), 256, 0, stream>>>(xpad, wtr1, b_in, xq, nullptr);
  // attention branches (write ypad interior)
  win_attn_kernel<<<dim3(1024, 2, Bc), 256, 0, stream>>>(xq, biasf, ls, ypad);
  row_attn_kernel<<<Bc * 160 * 8, 192, 0, stream>>>(xq, lrs, vrow);
  col_attn_kernel<<<Bc * 160 * 8, 192, 0, stream>>>(xq, lrs, vrow, ypad);
  // conv_out 192->192: grid (80, 3, 2)
  conv_mfma<192, 1><<<dim3(80, 3, Bc), 256, 0, stream>>>(ypad, wtr2, b_out, nullptr, out);
}

// Round 7
// 261.302 us; speedup vs baseline: 8.6701x; 1.0248x over previous
//
#include <hip/hip_runtime.h>
#include <math.h>

// GeoAB: conv3x3(192->384, bf16 MFMA, counted-vmcnt pipeline) -> [win+row attn | col attn]
//        -> conv3x3(192->192, bf16 MFMA).  B=2, H=W=160, WS=5, NH=8, CPH=8.

typedef __attribute__((ext_vector_type(8))) short short8;
typedef __attribute__((ext_vector_type(4))) short short4v;
typedef __attribute__((ext_vector_type(4))) float f32x4;

constexpr int Hc = 160, Wc = 160, Bc = 2;
constexpr int HPR = 162;   // padded rows
constexpr int HPW = 164;   // padded cols

__device__ inline unsigned short f2bf(float f) {
  union { float f; unsigned u; } v; v.f = f;
  unsigned r = v.u + 0x7FFF + ((v.u >> 16) & 1);
  return (unsigned short)(r >> 16);
}
__device__ inline float bf2f(unsigned short h) {
  union { unsigned u; float f; } v; v.u = ((unsigned)h) << 16;
  return v.f;
}

__device__ inline void gl16(const void* g, void* l) {
  __builtin_amdgcn_global_load_lds((const __attribute__((address_space(1))) unsigned int*)g,
                                   (__attribute__((address_space(3))) unsigned int*)l, 16, 0, 0);
}

__device__ inline float dot8(f32x4 a0, f32x4 a1, f32x4 b0, f32x4 b1) {
  float d = a0[0] * b0[0];
  d = fmaf(a0[1], b0[1], d); d = fmaf(a0[2], b0[2], d); d = fmaf(a0[3], b0[3], d);
  d = fmaf(a1[0], b1[0], d); d = fmaf(a1[1], b1[1], d);
  d = fmaf(a1[2], b1[2], d); d = fmaf(a1[3], b1[3], d);
  return d;
}

// ================= fused prep: nchw->nhwc pad | zero borders | weight xform x2 | cpb =================
// frag layout for weights: wtr[(((tap*6+cs)*NT + cotile)*64 + kh*16 + cor)*8 + j]
__global__ __launch_bounds__(256)
void prep_kernel(const float* __restrict__ x, unsigned short* __restrict__ xpad,
                 unsigned short* __restrict__ ypad,
                 const float* __restrict__ w_in, unsigned short* __restrict__ wtr1,
                 const float* __restrict__ w_out, unsigned short* __restrict__ wtr2,
                 const float* __restrict__ cw1, const float* __restrict__ cb1,
                 const float* __restrict__ cw2, float* __restrict__ biasf) {
  __shared__ float tile[192][33];
  const int bid = blockIdx.x;
  const int t = threadIdx.x;
  if (bid < 1600) {
    // ---- NCHW fp32 -> padded NHWC bf16 ----
    int blk = bid;
    const int w0 = (blk % 5) * 32; blk /= 5;
    const int h = blk % 160;
    const int b = blk / 160;
    for (int i = t; i < 192 * 32; i += 256) {
      int c = i >> 5, w = i & 31;
      tile[c][w] = x[(((size_t)b * 192 + c) * 160 + h) * 160 + w0 + w];
    }
    __syncthreads();
    for (int i = t; i < 32 * 192; i += 256) {
      int w = i / 192, c = i % 192;
      xpad[(((size_t)b * HPR + h + 1) * HPW + w0 + w + 1) * 192 + c] = f2bf(tile[c][w]);
    }
  } else if (bid < 1963) {
    // ---- zero borders of xpad/ypad ----
    const int NPOS = 968;
    const int total = 2 * 2 * NPOS * 24;
    int idx = (bid - 1600) * 256 + t;
    if (idx >= total) return;
    const int ch = idx % 24; int q = idx / 24;
    const int pos = q % NPOS; q /= NPOS;
    const int b = q & 1; const int buf = q >> 1;
    int row, col;
    if (pos < 328) { row = (pos < 164) ? 0 : 161; col = pos % 164; }
    else { int r = pos - 328; row = 1 + (r >> 2); int cm = r & 3; col = cm == 0 ? 0 : 160 + cm; }
    unsigned short* p = (buf ? ypad : xpad) + (((size_t)b * HPR + row) * HPW + col) * 192 + ch * 8;
    short8 z = {};
    *(short8*)p = z;
  } else if (bid < 2395) {
    // ---- weights OIHW fp32 -> per-fragment bf16 ----
    const bool first = bid < 2251;
    const int CO = first ? 384 : 192;
    const int NT = CO / 16;
    const float* w = first ? w_in : w_out;
    unsigned short* wtr = first ? wtr1 : wtr2;
    int id = (bid - (first ? 1963 : 2251)) * 256 + t;
    if (id >= CO * 192) return;
    const int co = id / 192, ci = id % 192;
    const int cs = ci >> 5, kh = (ci >> 3) & 3, j = ci & 7;
    const int cotile = co >> 4, cor = co & 15;
    const float* wp = w + (size_t)id * 9;
#pragma unroll
    for (int tap = 0; tap < 9; ++tap)
      wtr[((((size_t)tap * 6 + cs) * NT + cotile) * 64 + kh * 16 + cor) * 8 + j] = f2bf(wp[tap]);
  } else {
    // ---- CPB relative-position bias: 81 entries x 8 heads ----
    if (t >= 64) return;
    const int e = bid - 2395;
    const int d0 = e / 9, d1 = e % 9;
    const int r0 = d0 - 4, r1 = d1 - 4;
    float t0 = log2f(fabsf((float)r0) * 2.0f + 1.0f) * (1.0f / 3.0f); if (r0 < 0) t0 = -t0;
    float t1 = log2f(fabsf((float)r1) * 2.0f + 1.0f) * (1.0f / 3.0f); if (r1 < 0) t1 = -t1;
    const int lane = t;
    float acc[8];
#pragma unroll
    for (int n = 0; n < 8; ++n) acc[n] = 0.f;
    for (int k = lane; k < 512; k += 64) {
      float hk = fmaf(t0, cw1[k * 2 + 0], fmaf(t1, cw1[k * 2 + 1], cb1[k]));
      hk = fmaxf(hk, 0.f);
#pragma unroll
      for (int n = 0; n < 8; ++n) acc[n] = fmaf(hk, cw2[n * 512 + k], acc[n]);
    }
#pragma unroll
    for (int n = 0; n < 8; ++n) {
#pragma unroll
      for (int off = 32; off > 0; off >>= 1) acc[n] += __shfl_xor(acc[n], off, 64);
    }
    if (lane == 0) {
#pragma unroll
      for (int n = 0; n < 8; ++n)
        biasf[e * 8 + n] = 16.0f / (1.0f + expf(-acc[n]));
    }
  }
}

// ================= conv3x3 SAME, implicit GEMM, counted-vmcnt pipeline =================
// Block: 4 waves, one h-row each; wave tile 80w x 64co (acc 5x4). BH=4, slab R=6 rows, dbuf.
// Per cs: stage(next slab, 8 gl16) -> [GROUP(Ak,cs); LOADA(Ak,cs+1)] x3 -> vmcnt(36)+barrier.
// A-batches get >=2 groups of cover; gl16s stay counted (never drain to 0).
template<int COUT, int OUTMODE>
__global__ __launch_bounds__(256, 2)
void conv_mfma(const unsigned short* __restrict__ xin, const unsigned short* __restrict__ wtrA,
               const float* __restrict__ bias, unsigned short* __restrict__ obf,
               float* __restrict__ of32) {
  constexpr int CIN = 192;
  constexpr int R = 6;
  constexpr int TOTAL = R * 84 * 4;          // 2016 16B chunks per slab
  constexpr int SLAB = R * 84 * 32;          // shorts per buffer
  constexpr int NT = COUT / 16;
  __shared__ unsigned short slab[2 * SLAB];
  const int t = threadIdx.x, lane = t & 63, wid = t >> 6;
  const int bx = blockIdx.x, cog = blockIdx.y, b = blockIdx.z;
  const int ws = bx & 1, hb = bx >> 1;
  const int w0 = ws * 80, h0 = hb * 4;
  const int hr = wid;
  const int l15 = lane & 15, l4 = lane >> 4;
  const int co0 = cog * 64;

  f32x4 acc[5][4];
#pragma unroll
  for (int ct = 0; ct < 4; ++ct) {
    f32x4 bi;
#pragma unroll
    for (int r = 0; r < 4; ++r) bi[r] = bias[co0 + ct * 16 + l4 * 4 + r];
#pragma unroll
    for (int mt = 0; mt < 5; ++mt) acc[mt][ct] = bi;
  }

  auto stage = [&](int cs, int bufbase) {
#pragma unroll
    for (int ib0 = 0; ib0 < 8; ++ib0) {
      const int ib = ib0 * 4 + wid;
      const int n = ib * 64 + lane;
      if (n < TOTAL) {
        const int c = n & 3, q = n >> 2;
        const int r = q / 84, wv = q - r * 84;
        const int csrc = c ^ ((wv >> 1) & 3);
        const unsigned short* g = xin +
            (((size_t)b * HPR + h0 + r) * HPW + w0 + wv) * CIN + cs * 32 + csrc * 8;
        gl16(g, &slab[bufbase + ib * 512]);
      }
    }
  };

// load 12 A-frags (one ky group) into register array a
#define LOADA(a, ky, cs)                                                         \
  {                                                                              \
    _Pragma("unroll")                                                            \
    for (int kx = 0; kx < 3; ++kx) {                                             \
      _Pragma("unroll")                                                          \
      for (int ct = 0; ct < 4; ++ct)                                             \
        a[kx * 4 + ct] = *(const short8*)(wtrA +                                 \
            ((size_t)(((ky) * 3 + kx) * 6 + (cs)) * NT + cog * 4 + ct) * 512 +   \
            lane * 8);                                                           \
    }                                                                            \
  }

// 60 MFMAs of one ky group against slab buffer at bufbase
#define GROUP(a, ky, bufbase)                                                    \
  {                                                                              \
    const unsigned short* srow = &slab[(bufbase) + (hr + (ky)) * 84 * 32];       \
    _Pragma("unroll")                                                            \
    for (int kx = 0; kx < 3; ++kx) {                                             \
      _Pragma("unroll")                                                          \
      for (int mt = 0; mt < 5; ++mt) {                                           \
        const int wv = mt * 16 + l15 + kx;                                       \
        const int cr = l4 ^ ((wv >> 1) & 3);                                     \
        short8 bf = *(const short8*)(srow + wv * 32 + cr * 8);                   \
        _Pragma("unroll")                                                        \
        for (int ct = 0; ct < 4; ++ct)                                           \
          acc[mt][ct] =                                                          \
              __builtin_amdgcn_mfma_f32_16x16x32_bf16(a[kx * 4 + ct], bf,        \
                                                      acc[mt][ct], 0, 0, 0);     \
      }                                                                          \
    }                                                                            \
  }

// one cs step; A0f/A1f/A2f hold cs's fragments on entry, cs+1's on exit
#define CSBODY(cs, base, nbase, LAST)                                            \
  {                                                                              \
    if (!(LAST)) stage((cs) + 1, nbase);                                         \
    __builtin_amdgcn_s_setprio(1);                                               \
    GROUP(A0f, 0, base);                                                         \
    __builtin_amdgcn_s_setprio(0);                                               \
    if (!(LAST)) LOADA(A0f, 0, (cs) + 1);                                        \
    __builtin_amdgcn_s_setprio(1);                                               \
    GROUP(A1f, 1, base);                                                         \
    __builtin_amdgcn_s_setprio(0);                                               \
    if (!(LAST)) LOADA(A1f, 1, (cs) + 1);                                        \
    __builtin_amdgcn_s_setprio(1);                                               \
    GROUP(A2f, 2, base);                                                         \
    __builtin_amdgcn_s_setprio(0);                                               \
    if (!(LAST)) {                                                               \
      LOADA(A2f, 2, (cs) + 1);                                                   \
      asm volatile("s_waitcnt vmcnt(36)\n\ts_barrier" ::: "memory");             \
    }                                                                            \
  }

  short8 A0f[12], A1f[12], A2f[12];
  stage(0, 0);
  LOADA(A0f, 0, 0);
  LOADA(A1f, 1, 0);
  LOADA(A2f, 2, 0);
  asm volatile("s_waitcnt vmcnt(36)\n\ts_barrier" ::: "memory");

  CSBODY(0, 0, SLAB, 0);
  CSBODY(1, SLAB, 0, 0);
  CSBODY(2, 0, SLAB, 0);
  CSBODY(3, SLAB, 0, 0);
  CSBODY(4, 0, SLAB, 0);
  CSBODY(5, SLAB, 0, 1);
#undef LOADA
#undef GROUP
#undef CSBODY

  // ---- epilogue: D row = co (l4*4+r), col = w (l15) ----
  const int h = h0 + hr;
  if (OUTMODE == 0) {
#pragma unroll
    for (int mt = 0; mt < 5; ++mt) {
      const int w = w0 + mt * 16 + l15;
      unsigned short* dst0 = obf + (((size_t)b * Hc + h) * Wc + w) * 384 + co0 + l4 * 4;
#pragma unroll
      for (int ct = 0; ct < 4; ++ct) {
        short4v s;
#pragma unroll
        for (int r = 0; r < 4; ++r) s[r] = (short)f2bf(acc[mt][ct][r]);
        *(short4v*)(dst0 + ct * 16) = s;
      }
    }
  } else {
#pragma unroll
    for (int mt = 0; mt < 5; ++mt) {
      const int w = w0 + mt * 16 + l15;
#pragma unroll
      for (int ct = 0; ct < 4; ++ct)
#pragma unroll
        for (int r = 0; r < 4; ++r) {
          const int co = co0 + ct * 16 + l4 * 4 + r;
          of32[(((size_t)b * COUT + co) * Hc + h) * Wc + w] = acc[mt][ct][r];
        }
    }
  }
}

// ================= fused attn pass 1: window attn (both variants) + axial row pass =================
__global__ __launch_bounds__(256)
void attn1_kernel(const unsigned short* __restrict__ xq, const float* __restrict__ biasf,
                  const float* __restrict__ logit_scale, const float* __restrict__ lrs,
                  unsigned short* __restrict__ ypad, unsigned short* __restrict__ vrow) {
  const int bid = blockIdx.x;
  if (bid < 4096) {
    // ---- 5x5 window cosine attention ----
    __shared__ f32x4 kn4[8][25][2];
    __shared__ f32x4 vv4[8][25][2];
    const int head = threadIdx.x >> 5;
    const int i = threadIdx.x & 31;
    const int b = bid >> 11;
    const int r = bid & 2047;
    const int variant = r >> 10;
    const int blk = r & 1023;
    const int chan_off = variant ? 128 : 0;
    const int y_ch_off = variant ? 64 : 0;
    const int shift_in = variant ? 3 : 0;
    const int shift_out = variant ? 2 : 0;
    const int wb_i = blk % 32, hb_i = blk / 32;
    const int wi = i / 5, wj = i % 5;
    const int gh = hb_i * 5 + wi, gw = wb_i * 5 + wj;
    const int sh = (gh + shift_in) % Hc, sw = (gw + shift_in) % Wc;

    if (i < 25) {
      const unsigned short* base = xq + (((size_t)b * Hc + sh) * Wc + sw) * 384 + chan_off + head * 8;
      short8 kv = *(const short8*)base;
      short8 vv = *(const short8*)(base + 64);
      float k[8]; float nrm = 0.f;
#pragma unroll
      for (int c = 0; c < 8; ++c) { k[c] = bf2f((unsigned short)kv[c]); nrm = fmaf(k[c], k[c], nrm); }
      const float inv = 1.0f / fmaxf(sqrtf(nrm), 1e-12f);
      f32x4 a0, a1, b0, b1;
#pragma unroll
      for (int c = 0; c < 4; ++c) { a0[c] = k[c] * inv; a1[c] = k[c + 4] * inv; }
#pragma unroll
      for (int c = 0; c < 4; ++c) { b0[c] = bf2f((unsigned short)vv[c]); b1[c] = bf2f((unsigned short)vv[c + 4]); }
      kn4[head][i][0] = a0; kn4[head][i][1] = a1;
      vv4[head][i][0] = b0; vv4[head][i][1] = b1;
    }
    __syncthreads();
    if (i >= 25) return;

    const float scale = expf(fminf(logit_scale[head], 4.6051702f));
    const f32x4 q0 = kn4[head][i][0], q1 = kn4[head][i][1];
    float s[25];
#pragma unroll
    for (int j = 0; j < 25; ++j) {
      const float d = dot8(q0, q1, kn4[head][j][0], kn4[head][j][1]);
      const int d0 = wi - (j / 5) + 4, d1 = wj - (j % 5) + 4;
      s[j] = fmaf(d, scale, biasf[(d0 * 9 + d1) * 8 + head]);
    }
    float m = -1e30f;
#pragma unroll
    for (int j = 0; j < 25; ++j) m = fmaxf(m, s[j]);
    float den = 0.f;
    f32x4 acc0 = {0.f, 0.f, 0.f, 0.f}, acc1 = {0.f, 0.f, 0.f, 0.f};
#pragma unroll
    for (int j = 0; j < 25; ++j) {
      const float p = __expf(s[j] - m);
      den += p;
      acc0 += vv4[head][j][0] * p;
      acc1 += vv4[head][j][1] * p;
    }
    const float rden = 1.0f / den;
    const int oh = (gh + shift_out) % Hc, ow = (gw + shift_out) % Wc;
    short8 o;
#pragma unroll
    for (int c = 0; c < 4; ++c) { o[c] = (short)f2bf(acc0[c] * rden); o[c + 4] = (short)f2bf(acc1[c] * rden); }
    *(short8*)(ypad + (((size_t)b * HPR + oh + 1) * HPW + ow + 1) * 192 + y_ch_off + head * 8) = o;
  } else {
    // ---- axial row pass -> vrow bf16 [b][head][h][w][8] ----
    __shared__ f32x4 kn4[160][2];
    __shared__ f32x4 vv4[160][2];
    int u = bid - 4096;
    const int head = u % 8; u /= 8;
    const int h = u % 160;
    const int b = u / 160;
    const int i = threadIdx.x;

    if (i < 160) {
      const unsigned short* base = xq + (((size_t)b * Hc + h) * Wc + i) * 384 + 256 + head * 8;
      short8 kv = *(const short8*)base;
      short8 vv = *(const short8*)(base + 64);
      float k[8]; float nrm = 0.f;
#pragma unroll
      for (int c = 0; c < 8; ++c) { k[c] = bf2f((unsigned short)kv[c]); nrm = fmaf(k[c], k[c], nrm); }
      const float inv = 1.0f / fmaxf(sqrtf(nrm), 1e-12f);
      f32x4 a0, a1, b0, b1;
#pragma unroll
      for (int c = 0; c < 4; ++c) { a0[c] = k[c] * inv; a1[c] = k[c + 4] * inv; }
#pragma unroll
      for (int c = 0; c < 4; ++c) { b0[c] = bf2f((unsigned short)vv[c]); b1[c] = bf2f((unsigned short)vv[c + 4]); }
      kn4[i][0] = a0; kn4[i][1] = a1;
      vv4[i][0] = b0; vv4[i][1] = b1;
    }
    __syncthreads();
    if (i >= 160) return;

    const float scale = expf(fminf(lrs[head], 4.6051702f));
    const f32x4 q0 = kn4[i][0], q1 = kn4[i][1];
    float den = 0.f;
    f32x4 acc0 = {0.f, 0.f, 0.f, 0.f}, acc1 = {0.f, 0.f, 0.f, 0.f};
    for (int j = 0; j < 160; ++j) {
      const float d = dot8(q0, q1, kn4[j][0], kn4[j][1]);
      const float p = __expf(fmaf(d, scale, -scale));
      den += p;
      acc0 += vv4[j][0] * p;
      acc1 += vv4[j][1] * p;
    }
    const float rden = 1.0f / den;
    short8 o;
#pragma unroll
    for (int c = 0; c < 4; ++c) { o[c] = (short)f2bf(acc0[c] * rden); o[c + 4] = (short)f2bf(acc1[c] * rden); }
    *(short8*)(vrow + ((((size_t)b * 8 + head) * 160 + h) * 160 + i) * 8) = o;
  }
}

// ================= axial column pass -> ypad channels 128..191 =================
__global__ __launch_bounds__(192)
void col_attn_kernel(const unsigned short* __restrict__ xq, const float* __restrict__ lrs,
                     const unsigned short* __restrict__ vrow, unsigned short* __restrict__ ypad) {
  __shared__ f32x4 kn4[160][2];
  __shared__ f32x4 vv4[160][2];
  int blk = blockIdx.x;
  const int head = blk % 8; blk /= 8;
  const int w = blk % 160; blk /= 160;
  const int b = blk;
  const int i = threadIdx.x;

  if (i < 160) {
    const unsigned short* kb = xq + (((size_t)b * Hc + i) * Wc + w) * 384 + 256 + head * 8;
    short8 kv = *(const short8*)kb;
    short8 vv = *(const short8*)(vrow + ((((size_t)b * 8 + head) * 160 + i) * 160 + w) * 8);
    float k[8]; float nrm = 0.f;
#pragma unroll
    for (int c = 0; c < 8; ++c) { k[c] = bf2f((unsigned short)kv[c]); nrm = fmaf(k[c], k[c], nrm); }
    const float inv = 1.0f / fmaxf(sqrtf(nrm), 1e-12f);
    f32x4 a0, a1, b0, b1;
#pragma unroll
    for (int c = 0; c < 4; ++c) { a0[c] = k[c] * inv; a1[c] = k[c + 4] * inv; }
#pragma unroll
    for (int c = 0; c < 4; ++c) { b0[c] = bf2f((unsigned short)vv[c]); b1[c] = bf2f((unsigned short)vv[c + 4]); }
    kn4[i][0] = a0; kn4[i][1] = a1;
    vv4[i][0] = b0; vv4[i][1] = b1;
  }
  __syncthreads();
  if (i >= 160) return;

  const float scale = expf(fminf(lrs[head], 4.6051702f));
  const f32x4 q0 = kn4[i][0], q1 = kn4[i][1];
  float den = 0.f;
  f32x4 acc0 = {0.f, 0.f, 0.f, 0.f}, acc1 = {0.f, 0.f, 0.f, 0.f};
  for (int j = 0; j < 160; ++j) {
    const float d = dot8(q0, q1, kn4[j][0], kn4[j][1]);
    const float p = __expf(fmaf(d, scale, -scale));
    den += p;
    acc0 += vv4[j][0] * p;
    acc1 += vv4[j][1] * p;
  }
  const float rden = 1.0f / den;
  short8 o;
#pragma unroll
  for (int c = 0; c < 4; ++c) { o[c] = (short)f2bf(acc0[c] * rden); o[c + 4] = (short)f2bf(acc1[c] * rden); }
  *(short8*)(ypad + (((size_t)b * HPR + i + 1) * HPW + w + 1) * 192 + 128 + head * 8) = o;
}

extern "C" void kernel_launch(void* const* d_in, const int* in_sizes, int n_in,
                              void* d_out, int out_size, void* d_ws, size_t ws_size,
                              hipStream_t stream) {
  const float* x     = (const float*)d_in[0];
  const float* w_in  = (const float*)d_in[1];
  const float* b_in  = (const float*)d_in[2];
  const float* w_out = (const float*)d_in[3];
  const float* b_out = (const float*)d_in[4];
  const float* ls    = (const float*)d_in[5];
  const float* lrs   = (const float*)d_in[6];
  const float* cw1   = (const float*)d_in[7];
  const float* cb1   = (const float*)d_in[8];
  const float* cw2   = (const float*)d_in[9];
  float* out = (float*)d_out;

  // workspace layout
  char* p = (char*)d_ws;
  unsigned short* xpad = (unsigned short*)p;  p += (size_t)Bc * HPR * HPW * 192 * 2;   // 20.4 MB
  unsigned short* ypad = (unsigned short*)p;  p += (size_t)Bc * HPR * HPW * 192 * 2;   // 20.4 MB
  unsigned short* xq   = (unsigned short*)p;  p += (size_t)Bc * Hc * Wc * 384 * 2;     // 39.3 MB
  unsigned short* vrow = (unsigned short*)p;  p += (size_t)Bc * 8 * Hc * Wc * 8 * 2;   //  6.6 MB
  unsigned short* wtr1 = (unsigned short*)p;  p += (size_t)9 * 384 * 192 * 2;          //  1.3 MB
  unsigned short* wtr2 = (unsigned short*)p;  p += (size_t)9 * 192 * 192 * 2;          //  0.7 MB
  float* biasf = (float*)p;

  // 1) fused prep: nchw2nhwc (1600) | zero borders (363) | wxformA in (288) | wxformA out (144) | cpb (81)
  prep_kernel<<<2476, 256, 0, stream>>>(x, xpad, ypad, w_in, wtr1, w_out, wtr2, cw1, cb1, cw2, biasf);
  // 2) conv_in 192->384
  conv_mfma<384, 0><<<dim3(80, 6, Bc), 256, 0, stream>>>(xpad, wtr1, b_in, xq, nullptr);
  // 3) window attn (both variants) + axial row pass
  attn1_kernel<<<4096 + Bc * 160 * 8, 256, 0, stream>>>(xq, biasf, ls, lrs, ypad, vrow);
  // 4) axial column pass
  col_attn_kernel<<<Bc * 160 * 8, 192, 0, stream>>>(xq, lrs, vrow, ypad);
  // 5) conv_out 192->192
  conv_mfma<192, 1><<<dim3(80, 3, Bc), 256, 0, stream>>>(ypad, wtr2, b_out, nullptr, out);
}

// Round 10
// 239.767 us; speedup vs baseline: 9.4488x; 1.0898x over previous
//
#include <hip/hip_runtime.h>
#include <math.h>

// GeoAB: conv3x3(192->384, bf16 MFMA, counted-vmcnt pipeline) -> [win+row attn | col attn]
//        -> conv3x3(192->192, bf16 MFMA).  B=2, H=W=160, WS=5, NH=8, CPH=8.

typedef __attribute__((ext_vector_type(8))) short short8;
typedef __attribute__((ext_vector_type(4))) short short4v;
typedef __attribute__((ext_vector_type(4))) float f32x4;

constexpr int Hc = 160, Wc = 160, Bc = 2;
constexpr int HPR = 162;   // padded rows
constexpr int HPW = 164;   // padded cols

__device__ inline unsigned short f2bf(float f) {
  union { float f; unsigned u; } v; v.f = f;
  unsigned r = v.u + 0x7FFF + ((v.u >> 16) & 1);
  return (unsigned short)(r >> 16);
}
__device__ inline float bf2f(unsigned short h) {
  union { unsigned u; float f; } v; v.u = ((unsigned)h) << 16;
  return v.f;
}

__device__ inline void gl16(const void* g, void* l) {
  __builtin_amdgcn_global_load_lds((const __attribute__((address_space(1))) unsigned int*)g,
                                   (__attribute__((address_space(3))) unsigned int*)l, 16, 0, 0);
}

__device__ inline float dot8(f32x4 a0, f32x4 a1, f32x4 b0, f32x4 b1) {
  float d = a0[0] * b0[0];
  d = fmaf(a0[1], b0[1], d); d = fmaf(a0[2], b0[2], d); d = fmaf(a0[3], b0[3], d);
  d = fmaf(a1[0], b1[0], d); d = fmaf(a1[1], b1[1], d);
  d = fmaf(a1[2], b1[2], d); d = fmaf(a1[3], b1[3], d);
  return d;
}

// ================= fused prep: nchw->nhwc pad | zero borders | weight xform x2 | cpb =================
// frag layout for weights: wtr[(((tap*6+cs)*NT + cotile)*64 + kh*16 + cor)*8 + j]
__global__ __launch_bounds__(256)
void prep_kernel(const float* __restrict__ x, unsigned short* __restrict__ xpad,
                 unsigned short* __restrict__ ypad,
                 const float* __restrict__ w_in, unsigned short* __restrict__ wtr1,
                 const float* __restrict__ w_out, unsigned short* __restrict__ wtr2,
                 const float* __restrict__ cw1, const float* __restrict__ cb1,
                 const float* __restrict__ cw2, float* __restrict__ biasf) {
  __shared__ float tile[192][33];
  const int bid = blockIdx.x;
  const int t = threadIdx.x;
  if (bid < 1600) {
    // ---- NCHW fp32 -> padded NHWC bf16 ----
    int blk = bid;
    const int w0 = (blk % 5) * 32; blk /= 5;
    const int h = blk % 160;
    const int b = blk / 160;
    for (int i = t; i < 192 * 32; i += 256) {
      int c = i >> 5, w = i & 31;
      tile[c][w] = x[(((size_t)b * 192 + c) * 160 + h) * 160 + w0 + w];
    }
    __syncthreads();
    for (int i = t; i < 32 * 192; i += 256) {
      int w = i / 192, c = i % 192;
      xpad[(((size_t)b * HPR + h + 1) * HPW + w0 + w + 1) * 192 + c] = f2bf(tile[c][w]);
    }
  } else if (bid < 1963) {
    // ---- zero borders of xpad/ypad ----
    const int NPOS = 968;
    const int total = 2 * 2 * NPOS * 24;
    int idx = (bid - 1600) * 256 + t;
    if (idx >= total) return;
    const int ch = idx % 24; int q = idx / 24;
    const int pos = q % NPOS; q /= NPOS;
    const int b = q & 1; const int buf = q >> 1;
    int row, col;
    if (pos < 328) { row = (pos < 164) ? 0 : 161; col = pos % 164; }
    else { int r = pos - 328; row = 1 + (r >> 2); int cm = r & 3; col = cm == 0 ? 0 : 160 + cm; }
    unsigned short* p = (buf ? ypad : xpad) + (((size_t)b * HPR + row) * HPW + col) * 192 + ch * 8;
    short8 z = {};
    *(short8*)p = z;
  } else if (bid < 2395) {
    // ---- weights OIHW fp32 -> per-fragment bf16 ----
    const bool first = bid < 2251;
    const int CO = first ? 384 : 192;
    const int NT = CO / 16;
    const float* w = first ? w_in : w_out;
    unsigned short* wtr = first ? wtr1 : wtr2;
    int id = (bid - (first ? 1963 : 2251)) * 256 + t;
    if (id >= CO * 192) return;
    const int co = id / 192, ci = id % 192;
    const int cs = ci >> 5, kh = (ci >> 3) & 3, j = ci & 7;
    const int cotile = co >> 4, cor = co & 15;
    const float* wp = w + (size_t)id * 9;
#pragma unroll
    for (int tap = 0; tap < 9; ++tap)
      wtr[((((size_t)tap * 6 + cs) * NT + cotile) * 64 + kh * 16 + cor) * 8 + j] = f2bf(wp[tap]);
  } else {
    // ---- CPB relative-position bias: 81 entries x 8 heads ----
    if (t >= 64) return;
    const int e = bid - 2395;
    const int d0 = e / 9, d1 = e % 9;
    const int r0 = d0 - 4, r1 = d1 - 4;
    float t0 = log2f(fabsf((float)r0) * 2.0f + 1.0f) * (1.0f / 3.0f); if (r0 < 0) t0 = -t0;
    float t1 = log2f(fabsf((float)r1) * 2.0f + 1.0f) * (1.0f / 3.0f); if (r1 < 0) t1 = -t1;
    const int lane = t;
    float acc[8];
#pragma unroll
    for (int n = 0; n < 8; ++n) acc[n] = 0.f;
    for (int k = lane; k < 512; k += 64) {
      float hk = fmaf(t0, cw1[k * 2 + 0], fmaf(t1, cw1[k * 2 + 1], cb1[k]));
      hk = fmaxf(hk, 0.f);
#pragma unroll
      for (int n = 0; n < 8; ++n) acc[n] = fmaf(hk, cw2[n * 512 + k], acc[n]);
    }
#pragma unroll
    for (int n = 0; n < 8; ++n) {
#pragma unroll
      for (int off = 32; off > 0; off >>= 1) acc[n] += __shfl_xor(acc[n], off, 64);
    }
    if (lane == 0) {
#pragma unroll
      for (int n = 0; n < 8; ++n)
        biasf[e * 8 + n] = 16.0f / (1.0f + expf(-acc[n]));
    }
  }
}

// ================= conv3x3 SAME, implicit GEMM, counted-vmcnt pipeline =================
// Block: 4 waves, one h-row each; wave tile 80w x 64co (acc 5x4). BH=4, slab R=6 rows, dbuf.
// OUTMODE 0 epilogue: cog 0..3 -> xq NHWC [b][h][w][256]; cog 4 -> xk2k; cog 5 -> xk2v
//                     (head-major [b][head][h][w][8] bf16).
// OUTMODE 1 epilogue: fp32 NCHW out.
template<int COUT, int OUTMODE>
__global__ __launch_bounds__(256, 2)
void conv_mfma(const unsigned short* __restrict__ xin, const unsigned short* __restrict__ wtrA,
               const float* __restrict__ bias, unsigned short* __restrict__ obf,
               unsigned short* __restrict__ xk2k, unsigned short* __restrict__ xk2v,
               float* __restrict__ of32) {
  constexpr int CIN = 192;
  constexpr int R = 6;
  constexpr int TOTAL = R * 84 * 4;          // 2016 16B chunks per slab
  constexpr int SLAB = R * 84 * 32;          // shorts per buffer
  constexpr int NT = COUT / 16;
  __shared__ unsigned short slab[2 * SLAB];
  const int t = threadIdx.x, lane = t & 63, wid = t >> 6;
  const int bx = blockIdx.x, cog = blockIdx.y, b = blockIdx.z;
  const int ws = bx & 1, hb = bx >> 1;
  const int w0 = ws * 80, h0 = hb * 4;
  const int hr = wid;
  const int l15 = lane & 15, l4 = lane >> 4;
  const int co0 = cog * 64;

  f32x4 acc[5][4];
#pragma unroll
  for (int ct = 0; ct < 4; ++ct) {
    f32x4 bi;
#pragma unroll
    for (int r = 0; r < 4; ++r) bi[r] = bias[co0 + ct * 16 + l4 * 4 + r];
#pragma unroll
    for (int mt = 0; mt < 5; ++mt) acc[mt][ct] = bi;
  }

  auto stage = [&](int cs, int bufbase) {
#pragma unroll
    for (int ib0 = 0; ib0 < 8; ++ib0) {
      const int ib = ib0 * 4 + wid;
      const int n = ib * 64 + lane;
      if (n < TOTAL) {
        const int c = n & 3, q = n >> 2;
        const int r = q / 84, wv = q - r * 84;
        const int csrc = c ^ ((wv >> 1) & 3);
        const unsigned short* g = xin +
            (((size_t)b * HPR + h0 + r) * HPW + w0 + wv) * CIN + cs * 32 + csrc * 8;
        gl16(g, &slab[bufbase + ib * 512]);
      }
    }
  };

// load 12 A-frags (one ky group) into register array a
#define LOADA(a, ky, cs)                                                         \
  {                                                                              \
    _Pragma("unroll")                                                            \
    for (int kx = 0; kx < 3; ++kx) {                                             \
      _Pragma("unroll")                                                          \
      for (int ct = 0; ct < 4; ++ct)                                             \
        a[kx * 4 + ct] = *(const short8*)(wtrA +                                 \
            ((size_t)(((ky) * 3 + kx) * 6 + (cs)) * NT + cog * 4 + ct) * 512 +   \
            lane * 8);                                                           \
    }                                                                            \
  }

// 60 MFMAs of one ky group against slab buffer at bufbase
#define GROUP(a, ky, bufbase)                                                    \
  {                                                                              \
    const unsigned short* srow = &slab[(bufbase) + (hr + (ky)) * 84 * 32];       \
    _Pragma("unroll")                                                            \
    for (int kx = 0; kx < 3; ++kx) {                                             \
      _Pragma("unroll")                                                          \
      for (int mt = 0; mt < 5; ++mt) {                                           \
        const int wv = mt * 16 + l15 + kx;                                       \
        const int cr = l4 ^ ((wv >> 1) & 3);                                     \
        short8 bf = *(const short8*)(srow + wv * 32 + cr * 8);                   \
        _Pragma("unroll")                                                        \
        for (int ct = 0; ct < 4; ++ct)                                           \
          acc[mt][ct] =                                                          \
              __builtin_amdgcn_mfma_f32_16x16x32_bf16(a[kx * 4 + ct], bf,        \
                                                      acc[mt][ct], 0, 0, 0);     \
      }                                                                          \
    }                                                                            \
  }

// one cs step; A0f/A1f/A2f hold cs's fragments on entry, cs+1's on exit
#define CSBODY(cs, base, nbase, LAST)                                            \
  {                                                                              \
    if (!(LAST)) stage((cs) + 1, nbase);                                         \
    __builtin_amdgcn_s_setprio(1);                                               \
    GROUP(A0f, 0, base);                                                         \
    __builtin_amdgcn_s_setprio(0);                                               \
    if (!(LAST)) LOADA(A0f, 0, (cs) + 1);                                        \
    __builtin_amdgcn_s_setprio(1);                                               \
    GROUP(A1f, 1, base);                                                         \
    __builtin_amdgcn_s_setprio(0);                                               \
    if (!(LAST)) LOADA(A1f, 1, (cs) + 1);                                        \
    __builtin_amdgcn_s_setprio(1);                                               \
    GROUP(A2f, 2, base);                                                         \
    __builtin_amdgcn_s_setprio(0);                                               \
    if (!(LAST)) {                                                               \
      LOADA(A2f, 2, (cs) + 1);                                                   \
      asm volatile("s_waitcnt vmcnt(36)\n\ts_barrier" ::: "memory");             \
    }                                                                            \
  }

  short8 A0f[12], A1f[12], A2f[12];
  stage(0, 0);
  LOADA(A0f, 0, 0);
  LOADA(A1f, 1, 0);
  LOADA(A2f, 2, 0);
  asm volatile("s_waitcnt vmcnt(36)\n\ts_barrier" ::: "memory");

  CSBODY(0, 0, SLAB, 0);
  CSBODY(1, SLAB, 0, 0);
  CSBODY(2, 0, SLAB, 0);
  CSBODY(3, SLAB, 0, 0);
  CSBODY(4, 0, SLAB, 0);
  CSBODY(5, SLAB, 0, 1);
#undef LOADA
#undef GROUP
#undef CSBODY

  // ---- epilogue: D row = co (l4*4+r), col = w (l15) ----
  const int h = h0 + hr;
  if (OUTMODE == 0) {
    if (co0 < 256) {
#pragma unroll
      for (int mt = 0; mt < 5; ++mt) {
        const int w = w0 + mt * 16 + l15;
        unsigned short* dst0 = obf + (((size_t)b * Hc + h) * Wc + w) * 256 + co0 + l4 * 4;
#pragma unroll
        for (int ct = 0; ct < 4; ++ct) {
          short4v s;
#pragma unroll
          for (int r = 0; r < 4; ++r) s[r] = (short)f2bf(acc[mt][ct][r]);
          *(short4v*)(dst0 + ct * 16) = s;
        }
      }
    } else {
      unsigned short* xk2 = (co0 == 256) ? xk2k : xk2v;
#pragma unroll
      for (int mt = 0; mt < 5; ++mt) {
        const int w = w0 + mt * 16 + l15;
#pragma unroll
        for (int ct = 0; ct < 4; ++ct) {
          const int rel = ct * 16 + l4 * 4;
          const int head = rel >> 3, within = rel & 7;
          short4v s;
#pragma unroll
          for (int r = 0; r < 4; ++r) s[r] = (short)f2bf(acc[mt][ct][r]);
          *(short4v*)(xk2 + ((((size_t)b * 8 + head) * 160 + h) * 160 + w) * 8 + within) = s;
        }
      }
    }
  } else {
#pragma unroll
    for (int mt = 0; mt < 5; ++mt) {
      const int w = w0 + mt * 16 + l15;
#pragma unroll
      for (int ct = 0; ct < 4; ++ct)
#pragma unroll
        for (int r = 0; r < 4; ++r) {
          const int co = co0 + ct * 16 + l4 * 4 + r;
          of32[(((size_t)b * COUT + co) * Hc + h) * Wc + w] = acc[mt][ct][r];
        }
    }
  }
}

// ================= fused attn pass 1: window attn (both variants) + axial row pass =================
// win: lane map head = t&7, i = t>>3 -> 8 lanes read one pixel's contiguous 128B slice.
// row: reads head-major xk2k/xk2v -> consecutive threads read consecutive 16B.
__global__ __launch_bounds__(256)
void attn1_kernel(const unsigned short* __restrict__ xq, const float* __restrict__ biasf,
                  const float* __restrict__ logit_scale, const float* __restrict__ lrs,
                  const unsigned short* __restrict__ xk2k, const unsigned short* __restrict__ xk2v,
                  unsigned short* __restrict__ ypad, unsigned short* __restrict__ vrow) {
  const int bid = blockIdx.x;
  if (bid < 4096) {
    // ---- 5x5 window cosine attention ----
    __shared__ f32x4 kn4[8][25][2];
    __shared__ f32x4 vv4[8][25][2];
    const int t = threadIdx.x;
    const int head = t & 7;
    const int i = t >> 3;           // 0..31, active < 25
    const int b = bid >> 11;
    const int r = bid & 2047;
    const int variant = r >> 10;
    const int blk = r & 1023;
    const int chan_off = variant ? 128 : 0;
    const int y_ch_off = variant ? 64 : 0;
    const int shift_in = variant ? 3 : 0;
    const int shift_out = variant ? 2 : 0;
    const int wb_i = blk % 32, hb_i = blk / 32;
    const int wi = i / 5, wj = i % 5;
    const int gh = hb_i * 5 + wi, gw = wb_i * 5 + wj;
    const int sh = (gh + shift_in) % Hc, sw = (gw + shift_in) % Wc;

    if (i < 25) {
      const unsigned short* base = xq + (((size_t)b * Hc + sh) * Wc + sw) * 256 + chan_off + head * 8;
      short8 kv = *(const short8*)base;
      short8 vv = *(const short8*)(base + 64);
      float k[8]; float nrm = 0.f;
#pragma unroll
      for (int c = 0; c < 8; ++c) { k[c] = bf2f((unsigned short)kv[c]); nrm = fmaf(k[c], k[c], nrm); }
      const float inv = 1.0f / fmaxf(sqrtf(nrm), 1e-12f);
      f32x4 a0, a1, b0, b1;
#pragma unroll
      for (int c = 0; c < 4; ++c) { a0[c] = k[c] * inv; a1[c] = k[c + 4] * inv; }
#pragma unroll
      for (int c = 0; c < 4; ++c) { b0[c] = bf2f((unsigned short)vv[c]); b1[c] = bf2f((unsigned short)vv[c + 4]); }
      kn4[head][i][0] = a0; kn4[head][i][1] = a1;
      vv4[head][i][0] = b0; vv4[head][i][1] = b1;
    }
    __syncthreads();
    if (i >= 25) return;

    const float scale = expf(fminf(logit_scale[head], 4.6051702f));
    const f32x4 q0 = kn4[head][i][0], q1 = kn4[head][i][1];
    float s[25];
#pragma unroll
    for (int j = 0; j < 25; ++j) {
      const float d = dot8(q0, q1, kn4[head][j][0], kn4[head][j][1]);
      const int d0 = wi - (j / 5) + 4, d1 = wj - (j % 5) + 4;
      s[j] = fmaf(d, scale, biasf[(d0 * 9 + d1) * 8 + head]);
    }
    float m = -1e30f;
#pragma unroll
    for (int j = 0; j < 25; ++j) m = fmaxf(m, s[j]);
    float den = 0.f;
    f32x4 acc0 = {0.f, 0.f, 0.f, 0.f}, acc1 = {0.f, 0.f, 0.f, 0.f};
#pragma unroll
    for (int j = 0; j < 25; ++j) {
      const float p = __expf(s[j] - m);
      den += p;
      acc0 += vv4[head][j][0] * p;
      acc1 += vv4[head][j][1] * p;
    }
    const float rden = 1.0f / den;
    const int oh = (gh + shift_out) % Hc, ow = (gw + shift_out) % Wc;
    short8 o;
#pragma unroll
    for (int c = 0; c < 4; ++c) { o[c] = (short)f2bf(acc0[c] * rden); o[c + 4] = (short)f2bf(acc1[c] * rden); }
    *(short8*)(ypad + (((size_t)b * HPR + oh + 1) * HPW + ow + 1) * 192 + y_ch_off + head * 8) = o;
  } else {
    // ---- axial row pass -> vrow bf16 [b][head][h][w][8] ----
    __shared__ f32x4 kn4[160][2];
    __shared__ f32x4 vv4[160][2];
    int u = bid - 4096;
    const int head = u % 8; u /= 8;
    const int h = u % 160;
    const int b = u / 160;
    const int i = threadIdx.x;

    if (i < 160) {
      const size_t base = ((((size_t)b * 8 + head) * 160 + h) * 160 + i) * 8;
      short8 kv = *(const short8*)(xk2k + base);
      short8 vv = *(const short8*)(xk2v + base);
      float k[8]; float nrm = 0.f;
#pragma unroll
      for (int c = 0; c < 8; ++c) { k[c] = bf2f((unsigned short)kv[c]); nrm = fmaf(k[c], k[c], nrm); }
      const float inv = 1.0f / fmaxf(sqrtf(nrm), 1e-12f);
      f32x4 a0, a1, b0, b1;
#pragma unroll
      for (int c = 0; c < 4; ++c) { a0[c] = k[c] * inv; a1[c] = k[c + 4] * inv; }
#pragma unroll
      for (int c = 0; c < 4; ++c) { b0[c] = bf2f((unsigned short)vv[c]); b1[c] = bf2f((unsigned short)vv[c + 4]); }
      kn4[i][0] = a0; kn4[i][1] = a1;
      vv4[i][0] = b0; vv4[i][1] = b1;
    }
    __syncthreads();
    if (i >= 160) return;

    const float scale = expf(fminf(lrs[head], 4.6051702f));
    const f32x4 q0 = kn4[i][0], q1 = kn4[i][1];
    float den = 0.f;
    f32x4 acc0 = {0.f, 0.f, 0.f, 0.f}, acc1 = {0.f, 0.f, 0.f, 0.f};
    for (int j = 0; j < 160; ++j) {
      const float d = dot8(q0, q1, kn4[j][0], kn4[j][1]);
      const float p = __expf(fmaf(d, scale, -scale));
      den += p;
      acc0 += vv4[j][0] * p;
      acc1 += vv4[j][1] * p;
    }
    const float rden = 1.0f / den;
    short8 o;
#pragma unroll
    for (int c = 0; c < 4; ++c) { o[c] = (short)f2bf(acc0[c] * rden); o[c + 4] = (short)f2bf(acc1[c] * rden); }
    *(short8*)(vrow + ((((size_t)b * 8 + head) * 160 + h) * 160 + i) * 8) = o;
  }
}

// ================= axial column pass: block = (b, head, 4-col group), 640 threads =================
// stage k (xk2k) + v (vrow) for 4 columns with full-line coalesced loads, normalize into LDS,
// then 640 items (wi,i) each loop 160 j with broadcast LDS reads. Writes ypad ch 128..191.
__global__ __launch_bounds__(640)
void col_attn_kernel(const unsigned short* __restrict__ xk2k, const float* __restrict__ lrs,
                     const unsigned short* __restrict__ vrow, unsigned short* __restrict__ ypad) {
  __shared__ f32x4 knT[4][161][2];
  __shared__ f32x4 vvT[4][161][2];
  int blk = blockIdx.x;
  const int wg = blk % 40; blk /= 40;
  const int head = blk % 8;
  const int b = blk / 8;
  const int w0 = wg * 4;
  const int t = threadIdx.x;

  {
    const int h = t >> 2, wc = t & 3;
    const size_t base = ((((size_t)b * 8 + head) * 160 + h) * 160 + (w0 + wc)) * 8;
    short8 kv = *(const short8*)(xk2k + base);
    short8 vv = *(const short8*)(vrow + base);
    float k[8]; float nrm = 0.f;
#pragma unroll
    for (int c = 0; c < 8; ++c) { k[c] = bf2f((unsigned short)kv[c]); nrm = fmaf(k[c], k[c], nrm); }
    const float inv = 1.0f / fmaxf(sqrtf(nrm), 1e-12f);
    f32x4 a0, a1, b0, b1;
#pragma unroll
    for (int c = 0; c < 4; ++c) { a0[c] = k[c] * inv; a1[c] = k[c + 4] * inv; }
#pragma unroll
    for (int c = 0; c < 4; ++c) { b0[c] = bf2f((unsigned short)vv[c]); b1[c] = bf2f((unsigned short)vv[c + 4]); }
    knT[wc][h][0] = a0; knT[wc][h][1] = a1;
    vvT[wc][h][0] = b0; vvT[wc][h][1] = b1;
  }
  __syncthreads();

  const int wi = t / 160, i = t % 160;
  const float scale = expf(fminf(lrs[head], 4.6051702f));
  const f32x4 q0 = knT[wi][i][0], q1 = knT[wi][i][1];
  float den = 0.f;
  f32x4 acc0 = {0.f, 0.f, 0.f, 0.f}, acc1 = {0.f, 0.f, 0.f, 0.f};
  for (int j = 0; j < 160; ++j) {
    const float d = dot8(q0, q1, knT[wi][j][0], knT[wi][j][1]);
    const float p = __expf(fmaf(d, scale, -scale));
    den += p;
    acc0 += vvT[wi][j][0] * p;
    acc1 += vvT[wi][j][1] * p;
  }
  const float rden = 1.0f / den;
  short8 o;
#pragma unroll
  for (int c = 0; c < 4; ++c) { o[c] = (short)f2bf(acc0[c] * rden); o[c + 4] = (short)f2bf(acc1[c] * rden); }
  *(short8*)(ypad + (((size_t)b * HPR + i + 1) * HPW + w0 + wi + 1) * 192 + 128 + head * 8) = o;
}

extern "C" void kernel_launch(void* const* d_in, const int* in_sizes, int n_in,
                              void* d_out, int out_size, void* d_ws, size_t ws_size,
                              hipStream_t stream) {
  const float* x     = (const float*)d_in[0];
  const float* w_in  = (const float*)d_in[1];
  const float* b_in  = (const float*)d_in[2];
  const float* w_out = (const float*)d_in[3];
  const float* b_out = (const float*)d_in[4];
  const float* ls    = (const float*)d_in[5];
  const float* lrs   = (const float*)d_in[6];
  const float* cw1   = (const float*)d_in[7];
  const float* cb1   = (const float*)d_in[8];
  const float* cw2   = (const float*)d_in[9];
  float* out = (float*)d_out;

  // workspace layout
  char* p = (char*)d_ws;
  unsigned short* xpad = (unsigned short*)p;  p += (size_t)Bc * HPR * HPW * 192 * 2;   // 20.4 MB
  unsigned short* ypad = (unsigned short*)p;  p += (size_t)Bc * HPR * HPW * 192 * 2;   // 20.4 MB
  unsigned short* xq   = (unsigned short*)p;  p += (size_t)Bc * Hc * Wc * 256 * 2;     // 26.2 MB
  unsigned short* xk2k = (unsigned short*)p;  p += (size_t)Bc * 8 * Hc * Wc * 8 * 2;   //  6.6 MB
  unsigned short* xk2v = (unsigned short*)p;  p += (size_t)Bc * 8 * Hc * Wc * 8 * 2;   //  6.6 MB
  unsigned short* vrow = (unsigned short*)p;  p += (size_t)Bc * 8 * Hc * Wc * 8 * 2;   //  6.6 MB
  unsigned short* wtr1 = (unsigned short*)p;  p += (size_t)9 * 384 * 192 * 2;          //  1.3 MB
  unsigned short* wtr2 = (unsigned short*)p;  p += (size_t)9 * 192 * 192 * 2;          //  0.7 MB
  float* biasf = (float*)p;

  // 1) fused prep
  prep_kernel<<<2476, 256, 0, stream>>>(x, xpad, ypad, w_in, wtr1, w_out, wtr2, cw1, cb1, cw2, biasf);
  // 2) conv_in 192->384 (xq + xk2k/xk2v epilogue)
  conv_mfma<384, 0><<<dim3(80, 6, Bc), 256, 0, stream>>>(xpad, wtr1, b_in, xq, xk2k, xk2v, nullptr);
  // 3) window attn (both variants) + axial row pass
  attn1_kernel<<<4096 + Bc * 160 * 8, 256, 0, stream>>>(xq, biasf, ls, lrs, xk2k, xk2v, ypad, vrow);
  // 4) axial column pass
  col_attn_kernel<<<Bc * 8 * 40, 640, 0, stream>>>(xk2k, lrs, vrow, ypad);
  // 5) conv_out 192->192
  conv_mfma<192, 1><<<dim3(80, 3, Bc), 256, 0, stream>>>(ypad, wtr2, b_out, nullptr, nullptr, nullptr, out);
}